// Round 3
// baseline (844.521 us; speedup 1.0000x reference)
//
#include <hip/hip_runtime.h>
#include <math.h>

#define BATCH 8
constexpr float DXC   = 2.0f/31.0f;
constexpr float DXDY  = DXC*DXC;
constexpr float SCALE = 0.125f;      // 1/sqrt(64), folded into M/u/v/c
constexpr float EPSC  = 1e-5f;
constexpr float SLOPEC= 0.01f;

// ---- workspace float offsets ----
#define OFF_BAR    0u         // 16  (barrier cnt/gen; memset each launch)
#define OFF_LNP    16u        // 256
#define OFF_M      272u       // 16384
#define OFF_U      16656u     // 256
#define OFF_V      16912u     // 256
#define OFF_C      17168u     // 16 (+pad)
#define OFF_GS     17200u     // 512
#define OFF_WSPART 17712u     // 4096
#define OFF_VIN    21824u     // 1048576
#define OFF_W      1070400u   // 1048576
#define OFF_WF     2118976u   // 1048576
#define OFF_GPART  3167552u   // 1048576
#define OFF_GSPART 4216128u   // 16384
#define OFF_G      4232512u   // 32768
#define OFF_P      4265280u   // 524288
// total 4789568 floats = 19.2 MB (round-2 used 26.2 MB OK)

typedef float f2 __attribute__((ext_vector_type(2)));
static __device__ __forceinline__ f2 pkfma(f2 a, f2 b, f2 c){
  f2 d; asm("v_pk_fma_f32 %0, %1, %2, %3" : "=v"(d) : "v"(a), "v"(b), "v"(c)); return d;
}

__device__ __forceinline__ float lrelu(float x){ return fmaxf(x, SLOPEC*x); }

__device__ __forceinline__ float wsum64(float v){
  #pragma unroll
  for(int off=32; off; off>>=1) v += __shfl_xor(v, off);
  return v;
}

// device-wide barrier: requires all 256 blocks resident (1 block/CU).
__device__ __forceinline__ void gbar(unsigned* bar){
  __syncthreads();                       // drains each wave's vmcnt before s_barrier
  if(threadIdx.x==0){
    __threadfence();                     // release: block's writes visible device-wide
    unsigned g = atomicAdd(&bar[1], 0u); // read current generation
    unsigned a = atomicAdd(&bar[0], 1u);
    if(a==255u){
      atomicAnd(&bar[0], 0u);            // reset count (all arrived, nobody touches it)
      __threadfence();
      atomicAdd(&bar[1], 1u);            // release generation
    } else {
      while(atomicAdd(&bar[1], 0u)==g) __builtin_amdgcn_s_sleep(2);
    }
    __threadfence();                     // acquire: invalidate stale cache lines
  }
  __syncthreads();
}

// ---------------- edge MLPs: fused first-layer + packed-fp32 second layer ----------
__global__ __launch_bounds__(256) void k_mlp(
    const float* __restrict__ kW0, const float* __restrict__ kb0,
    const float* __restrict__ kW1, const float* __restrict__ kb1,
    const float* __restrict__ kW2, const float* __restrict__ kb2,
    const float* __restrict__ fW0, const float* __restrict__ fb0,
    const float* __restrict__ fW1, const float* __restrict__ fb1,
    const float* __restrict__ fW2, const float* __restrict__ fb2,
    float* __restrict__ w_out, float* __restrict__ wf_out)
{
  int blk = blockIdx.x;                  // 8192 = which(2) x i(1024) x sub(4)
  int which = blk>>12;
  int i = (blk&4095)>>2;
  int j = ((blk&3)<<8) | threadIdx.x;
  const float* W0 = which? fW0:kW0; const float* b0 = which? fb0:kb0;
  const float* W1 = which? fW1:kW1; const float* b1 = which? fb1:kb1;
  const float* W2 = which? fW2:kW2; const float* b2 = which? fb2:kb2;
  float* outp = which? wf_out : w_out;
  float xi = -1.f + DXC*(float)(i>>5), yi = -1.f + DXC*(float)(i&31);
  float xj = -1.f + DXC*(float)(j>>5), yj = -1.f + DXC*(float)(j&31);
  f2 H[16];
  #pragma unroll
  for(int c=0;c<16;c++){
    const float4* w0p = (const float4*)(W0 + c*8);
    float4 ra = w0p[0], rb = w0p[1];
    float ha = lrelu(ra.x*xi + ra.y*yi + ra.z*xj + ra.w*yj + b0[2*c]);
    float hb = lrelu(rb.x*xi + rb.y*yi + rb.z*xj + rb.w*yj + b0[2*c+1]);
    H[c] = f2{ha, hb};
  }
  float a = b2[0];
  #pragma unroll 2
  for(int o=0;o<64;o++){
    const float4* wrow = (const float4*)(W1 + o*32);  // uniform vector loads (L1 broadcast)
    f2 s = f2{b1[o], 0.f};
    #pragma unroll
    for(int k4=0;k4<8;k4++){
      float4 w = wrow[k4];
      s = pkfma(f2{w.x, w.y}, H[2*k4],   s);
      s = pkfma(f2{w.z, w.w}, H[2*k4+1], s);
    }
    a += W2[o]*lrelu(s.x + s.y);
  }
  outp[i*1024+j] = a;
}

// ---------------- Gram of a 64x64 LDS tile: gp[c*64+f] = sum_m sA[m][c]*sB[m][f] ----
__device__ __forceinline__ void gram_tile(const float* sA, const float* sB,
    int wid, int lane, float* __restrict__ gp, float* __restrict__ gsp)
{
  float acc[16];
  #pragma unroll
  for(int q=0;q<16;q++) acc[q]=0.f;
  float gsa=0.f;
  for(int m=0;m<64;m++){
    const float4* cp = (const float4*)(sA + m*64 + wid*16);  // wave-uniform -> broadcast
    float bml = sB[m*64+lane];
    float4 a0=cp[0],a1=cp[1],a2=cp[2],a3=cp[3];
    acc[0]+=a0.x*bml; acc[1]+=a0.y*bml; acc[2]+=a0.z*bml; acc[3]+=a0.w*bml;
    acc[4]+=a1.x*bml; acc[5]+=a1.y*bml; acc[6]+=a1.z*bml; acc[7]+=a1.w*bml;
    acc[8]+=a2.x*bml; acc[9]+=a2.y*bml; acc[10]+=a2.z*bml; acc[11]+=a2.w*bml;
    acc[12]+=a3.x*bml; acc[13]+=a3.y*bml; acc[14]+=a3.z*bml; acc[15]+=a3.w*bml;
    gsa += bml;
  }
  #pragma unroll
  for(int q=0;q<16;q++) gp[(wid*16+q)*64+lane]=acc[q];
  if(wid==0) gsp[lane]=gsa;
}

// ---------------- T[r*64+f] = u[r]*gs[f] + sum_c M[r][c]*G[c*64+f]; tv = v^T G + c*gs -
__device__ __forceinline__ void build_T(const float* __restrict__ Gsrc,
    const float* __restrict__ Mj, const float* __restrict__ uj,
    const float* __restrict__ vj, float cj, const float* __restrict__ gsrc,
    int wid, int lane, float* __restrict__ sT, float* __restrict__ stv)
{
  float gv[64];
  #pragma unroll
  for(int c=0;c<64;c++) gv[c]=Gsrc[c*64+lane];
  float gsl = gsrc[lane];
  float tacc = cj*gsl;
  #pragma unroll
  for(int c=0;c<64;c++) tacc += vj[c]*gv[c];
  #pragma unroll
  for(int r=0;r<16;r++){
    const float* mrow = Mj + (wid*16+r)*64;       // wave-uniform -> s_load
    float acc = uj[wid*16+r]*gsl;
    #pragma unroll
    for(int c=0;c<64;c++) acc += mrow[c]*gv[c];
    sT[(wid*16+r)*64+lane]=acc;
  }
  if(wid==0) stv[lane]=tacc;
}

// ---------------- persistent kernel: everything after k_mlp, 10 grid barriers -------
__global__ __launch_bounds__(256) void k_coop(
    const float* __restrict__ xy,
    const float* __restrict__ Wq, const float* __restrict__ bq,
    const float* __restrict__ Wk, const float* __restrict__ bk,
    const float* __restrict__ ln0g, const float* __restrict__ ln0b,
    const float* __restrict__ lng, const float* __restrict__ lnb,
    float* __restrict__ ws, float* __restrict__ out)
{
  __shared__ float smem[12352];                   // 49.4 KB
  unsigned* bar = (unsigned*)ws;
  float* lnp    = ws+OFF_LNP;
  float* Mg     = ws+OFF_M;
  float* ug     = ws+OFF_U;
  float* vg     = ws+OFF_V;
  float* cg     = ws+OFF_C;
  float* gsg    = ws+OFF_GS;
  float* wspart = ws+OFF_WSPART;
  float* Vin    = ws+OFF_VIN;
  float* weight = ws+OFF_W;
  float* weightf= ws+OFF_WF;
  float* Gpart  = ws+OFF_GPART;
  float* gspart = ws+OFF_GSPART;
  float* G      = ws+OFF_G;
  float* Pg     = ws+OFF_P;

  int blk = blockIdx.x, tid = threadIdx.x;
  int lane = tid&63;
  int wid = __builtin_amdgcn_readfirstlane(tid>>6);

  // ================= P0: LN0 partials | prep M,u,v,c | weight colsums =================
  if(blk<128){
    int b=blk>>4, seg=blk&15;
    const float4* x4=(const float4*)(xy + (size_t)b*131072 + seg*8192);
    float s=0.f, ss=0.f;
    #pragma unroll
    for(int k2=0;k2<8;k2++){
      float4 v=x4[tid+k2*256];
      s  += v.x+v.y+v.z+v.w;
      ss += v.x*v.x+v.y*v.y+v.z*v.z+v.w*v.w;
    }
    s=wsum64(s); ss=wsum64(ss);
    if(lane==0){ smem[wid]=s; smem[4+wid]=ss; }
    __syncthreads();
    if(tid==0){
      lnp[(b*16+seg)*2  ]=smem[0]+smem[1]+smem[2]+smem[3];
      lnp[(b*16+seg)*2+1]=smem[4]+smem[5]+smem[6]+smem[7];
    }
  } else if(blk<132){
    int j=blk-128;
    float mac[16], uac[16];
    #pragma unroll
    for(int r=0;r<16;r++){ mac[r]=0.f; uac[r]=0.f; }
    float vac=0.f, cac=0.f;
    for(int hk=0;hk<256;hk++){
      const float* wqrow = Wq + ((size_t)j*256+hk)*64;
      const float* wkrow = Wk + ((size_t)j*256+hk)*64;
      float wkl = wkrow[lane];
      float bkk = bk[j*256+hk], bqk = bq[j*256+hk];
      #pragma unroll
      for(int r=0;r<16;r++){ float wq=wqrow[wid*16+r]; mac[r]+=wq*wkl; uac[r]+=wq*bkk; }
      vac += bqk*wkl; cac += bqk*bkk;
    }
    #pragma unroll
    for(int r=0;r<16;r++) Mg[j*4096+(wid*16+r)*64+lane]=mac[r]*SCALE;
    if(lane==0){
      #pragma unroll
      for(int r=0;r<16;r++) ug[j*64+wid*16+r]=uac[r]*SCALE;
    }
    if(wid==0) vg[j*64+lane]=vac*SCALE;
    if(tid==0) cg[j]=cac*SCALE;
  } else if(blk<148){
    int w=blk-132;
    int jj=w*64+lane, q=wid;
    float s=0.f;
    for(int n=q*256;n<q*256+256;n++) s += weight[n*1024+jj] + weightf[n*1024+jj];
    wspart[jj*4+q]=s;
  }
  gbar(bar);

  // ================= P1: LN0 apply + Gram ============================================
  {
    int b=blk>>5, ch=blk&31;
    float s=0.f, ss=0.f;
    #pragma unroll
    for(int k2=0;k2<16;k2++){ s+=lnp[(b*16+k2)*2]; ss+=lnp[(b*16+k2)*2+1]; }
    float mean=s*(1.f/131072.f);
    float var =ss*(1.f/131072.f)-mean*mean;
    float inv =1.f/sqrtf(var+EPSC);
    float* sV=smem;
    const float4* x4=(const float4*)(xy   + ((size_t)b*2048+ch*64)*64);
    const float4* g4=(const float4*)(ln0g + (size_t)ch*4096);
    const float4* b4=(const float4*)(ln0b + (size_t)ch*4096);
    float4* vo4=(float4*)(Vin + ((size_t)b*2048+ch*64)*64);
    float4* sv4=(float4*)sV;
    for(int e=tid;e<1024;e+=256){
      float4 xv=x4[e], gv=g4[e], bv=b4[e]; float4 r;
      r.x=(xv.x-mean)*inv*gv.x+bv.x;
      r.y=(xv.y-mean)*inv*gv.y+bv.y;
      r.z=(xv.z-mean)*inv*gv.z+bv.z;
      r.w=(xv.w-mean)*inv*gv.w+bv.w;
      vo4[e]=r; sv4[e]=r;
    }
    __syncthreads();
    gram_tile(sV, sV, wid, lane, Gpart+((size_t)(b*32+ch))*4096, gspart+(b*32+ch)*64);
  }

  // ================= layers j=0..2 ====================================================
  for(int j=0;j<3;j++){
    gbar(bar);
    // P2: G-reduce (32 blocks)
    if(blk<32){
      int b=blk>>2, q=blk&3;
      for(int k=0;k<4;k++){
        int e=q*1024 + k*256 + tid;
        float s=0.f;
        for(int ch=0;ch<32;ch++) s+=Gpart[((size_t)(b*32+ch))*4096+e];
        G[b*4096+e]=s;
      }
      if(q==0 && tid<64){
        float s=0.f;
        for(int ch=0;ch<32;ch++) s+=gspart[(b*32+ch)*64+tid];
        gsg[b*64+tid]=s;
      }
    }
    gbar(bar);
    // P3: redundant T-build + mid + rowLN + residual + gram
    {
      int b=blk>>5, ch=blk&31;
      float* sV = smem; float* sT = smem+4096; float* stv = smem+8192; float* sX = smem+8256;
      float* vbase = Vin + ((size_t)b*2048+ch*64)*64;
      { const float4* vb4=(const float4*)vbase; float4* sv4=(float4*)sV;
        for(int e=tid;e<1024;e+=256) sv4[e]=vb4[e]; }
      build_T(G+b*4096, Mg+j*4096, ug+j*64, vg+j*64, cg[j], gsg+b*64, wid, lane, sT, stv);
      __syncthreads();
      float Tcol[64];
      #pragma unroll
      for(int c=0;c<64;c++) Tcol[c]=sT[c*64+lane];
      float tvl=stv[lane];
      float gl=lng[j*64+lane], bl=lnb[j*64+lane];
      for(int rr=0;rr<16;rr++){
        int r=wid*16+rr;
        const float4* rp=(const float4*)(sV + r*64);
        float vold = sV[r*64+lane];
        float m=tvl;
        #pragma unroll
        for(int c4=0;c4<16;c4++){
          float4 vv=rp[c4];
          m += vv.x*Tcol[c4*4]+vv.y*Tcol[c4*4+1]+vv.z*Tcol[c4*4+2]+vv.w*Tcol[c4*4+3];
        }
        m*=DXDY;
        float mean=wsum64(m)*(1.f/64.f);
        float d=m-mean;
        float var=wsum64(d*d)*(1.f/64.f);
        float y=d*(1.f/sqrtf(var+EPSC))*gl+bl+vold;
        vbase[r*64+lane]=y;
        sV[r*64+lane]=y;
      }
      __syncthreads();
      if(j<2){
        gram_tile(sV, sV, wid, lane, Gpart+((size_t)(b*32+ch))*4096, gspart+(b*32+ch)*64);
      } else if(ch<16){
        const float4* x4=(const float4*)(xy + ((size_t)b*2048+ch*64)*64);
        float4* sx4=(float4*)sX;
        for(int e=tid;e<1024;e+=256) sx4[e]=x4[e];
        __syncthreads();
        gram_tile(sV, sX, wid, lane, Gpart+((size_t)(b*16+ch))*4096, gspart+(b*16+ch)*64);
      }
    }
  }

  gbar(bar);
  // ================= P4: P = weight^T@Vu + weightf^T@Vf ==============================
  {
    int b=blk>>5, jjc=blk&31;
    int jj0=jjc*32+wid*8;
    const float* Vu = Vin + (size_t)b*131072;
    const float* Vf = Vu + 65536;
    float acc[8];
    #pragma unroll
    for(int q=0;q<8;q++) acc[q]=0.f;
    for(int n=0;n<1024;n++){
      float vu=Vu[n*64+lane], vf=Vf[n*64+lane];
      const float4* wp =(const float4*)(weight  + n*1024 + jj0);
      const float4* wfp=(const float4*)(weightf + n*1024 + jj0);
      float4 wa=wp[0], wb=wp[1], fa=wfp[0], fb=wfp[1];
      acc[0]+=wa.x*vu+fa.x*vf; acc[1]+=wa.y*vu+fa.y*vf;
      acc[2]+=wa.z*vu+fa.z*vf; acc[3]+=wa.w*vu+fa.w*vf;
      acc[4]+=wb.x*vu+fb.x*vf; acc[5]+=wb.y*vu+fb.y*vf;
      acc[6]+=wb.z*vu+fb.z*vf; acc[7]+=wb.w*vu+fb.w*vf;
    }
    #pragma unroll
    for(int q=0;q<8;q++) Pg[((size_t)(b*1024)+jj0+q)*64+lane]=acc[q];
  }
  gbar(bar);
  // ================= P5: out = dxdy^2*(P@T3 + wsm (x) t3) ============================
  {
    int b=blk>>5, rg=blk&31;
    float* sG=smem; float* sT3=smem+4096; float* stv=smem+8192; float* sGS=smem+8256;
    for(int e=tid;e<4096;e+=256){
      float s=0.f;
      for(int ch=0;ch<16;ch++) s+=Gpart[((size_t)(b*16+ch))*4096+e];
      sG[e]=s;
    }
    if(tid<64){
      float s=0.f;
      for(int ch=0;ch<16;ch++) s+=gspart[(b*16+ch)*64+tid];
      sGS[tid]=s;
    }
    __syncthreads();
    build_T(sG, Mg+3*4096, ug+3*64, vg+3*64, cg[3], sGS, wid, lane, sT3, stv);
    __syncthreads();
    float Tcol[64];
    #pragma unroll
    for(int c=0;c<64;c++) Tcol[c]=sT3[c*64+lane];
    float t3l=stv[lane];
    for(int rw=0;rw<8;rw++){
      int jj=rg*32+wid*8+rw;
      float p=Pg[((size_t)(b*1024)+jj)*64+lane];
      float wsm=wspart[jj*4]+wspart[jj*4+1]+wspart[jj*4+2]+wspart[jj*4+3];
      float acc=wsm*t3l;
      #pragma unroll
      for(int c=0;c<64;c++) acc += __shfl(p,c)*Tcol[c];
      out[((size_t)(b*1024)+jj)*64+lane]=acc*(DXDY*DXDY);
    }
  }
}

extern "C" void kernel_launch(void* const* d_in, const int* in_sizes, int n_in,
                              void* d_out, int out_size, void* d_ws, size_t ws_size,
                              hipStream_t stream)
{
  (void)in_sizes; (void)n_in; (void)out_size; (void)ws_size;
  const float* xy   = (const float*)d_in[0];
  const float* kW0  = (const float*)d_in[1];
  const float* kb0  = (const float*)d_in[2];
  const float* kW1  = (const float*)d_in[3];
  const float* kb1  = (const float*)d_in[4];
  const float* kW2  = (const float*)d_in[5];
  const float* kb2  = (const float*)d_in[6];
  const float* fW0  = (const float*)d_in[7];
  const float* fb0  = (const float*)d_in[8];
  const float* fW1  = (const float*)d_in[9];
  const float* fb1  = (const float*)d_in[10];
  const float* fW2  = (const float*)d_in[11];
  const float* fb2  = (const float*)d_in[12];
  const float* Wq   = (const float*)d_in[13];
  const float* bq   = (const float*)d_in[14];
  const float* Wk   = (const float*)d_in[15];
  const float* bk   = (const float*)d_in[16];
  const float* ln0g = (const float*)d_in[17];
  const float* ln0b = (const float*)d_in[18];
  const float* lng  = (const float*)d_in[19];
  const float* lnb  = (const float*)d_in[20];
  float* out = (float*)d_out;
  float* ws  = (float*)d_ws;

  // zero the barrier state (d_ws is poisoned to 0xAA once before timing)
  hipMemsetAsync(d_ws, 0, 256, stream);

  k_mlp<<<8192, 256, 0, stream>>>(kW0,kb0,kW1,kb1,kW2,kb2,
                                  fW0,fb0,fW1,fb1,fW2,fb2,
                                  ws+OFF_W, ws+OFF_WF);

  k_coop<<<256, 256, 0, stream>>>(xy, Wq,bq,Wk,bk, ln0g,ln0b, lng,lnb, ws, out);
}

// Round 4
// 439.438 us; speedup vs baseline: 1.9218x; 1.9218x over previous
//
#include <hip/hip_runtime.h>
#include <math.h>

#define BATCH 8
constexpr float DXC   = 2.0f/31.0f;
constexpr float DXDY  = DXC*DXC;
constexpr float SCALE = 0.125f;      // 1/sqrt(64), folded into M/u/v/c
constexpr float EPSC  = 1e-5f;
constexpr float SLOPEC= 0.01f;

// ---- workspace float offsets ----
#define OFF_LNP    0u         // 256
#define OFF_M      256u       // 16384
#define OFF_U      16640u     // 256
#define OFF_V      16896u     // 256
#define OFF_C      17152u     // 16
#define OFF_WSPART 17168u     // 2048 (2 ns-partials x 1024)
#define OFF_AIK    19216u     // 32768
#define OFF_BJK    51984u     // 32768
#define OFF_AIF    84752u     // 32768
#define OFF_BJF    117520u    // 32768
#define OFF_VIN    150288u    // 1048576
#define OFF_W      1198864u   // 1048576
#define OFF_WF     2247440u   // 1048576
#define OFF_GPA    3296016u   // 1048576  (gram partials, buffer A)
#define OFF_GSA    4344592u   // 16384
#define OFF_GPB    4360976u   // 1048576  (buffer B; also holds final cross-gram)
#define OFF_GSB    5409552u   // 16384
#define OFF_P      5425936u   // 1048576  (2 ns-partials x 8b x 1024jj x 64f)
// total 6474512 floats = 25.9 MB (26.2 MB worked in round 2)

__device__ __forceinline__ float lrelu(float x){ return fmaxf(x, SLOPEC*x); }

__device__ __forceinline__ float wsum64(float v){
  #pragma unroll
  for(int off=32; off; off>>=1) v += __shfl_xor(v, off);
  return v;
}

// ---------------- P0: edge tables + LN0 partial sums + M/u/v/c prep ----------------
__global__ __launch_bounds__(256) void k_pre0(
    const float* __restrict__ kW0, const float* __restrict__ kb0,
    const float* __restrict__ fW0, const float* __restrict__ fb0,
    const float* __restrict__ xy,
    const float* __restrict__ Wq, const float* __restrict__ bq,
    const float* __restrict__ Wk, const float* __restrict__ bk,
    float* __restrict__ ws)
{
  int blk = blockIdx.x, tid = threadIdx.x;
  int lane = tid&63;
  int wid = __builtin_amdgcn_readfirstlane(tid>>6);
  if(blk<128){
    // tables for 8 i-values
    {
      int i = blk*8 + (tid>>5), c = tid&31;
      float x = -1.f + DXC*(float)(i>>5);
      float y = -1.f + DXC*(float)(i&31);
      ws[OFF_AIK + i*32 + c] = kW0[c*4+0]*x + kW0[c*4+1]*y;
      ws[OFF_BJK + i*32 + c] = kW0[c*4+2]*x + kW0[c*4+3]*y + kb0[c];
      ws[OFF_AIF + i*32 + c] = fW0[c*4+0]*x + fW0[c*4+1]*y;
      ws[OFF_BJF + i*32 + c] = fW0[c*4+2]*x + fW0[c*4+3]*y + fb0[c];
    }
    // LN0 partial sums
    int b = blk>>4, seg = blk&15;
    const float4* x4 = (const float4*)(xy + (size_t)b*131072 + seg*8192);
    float s=0.f, ss=0.f;
    #pragma unroll
    for(int k2=0;k2<8;k2++){
      float4 v = x4[tid + k2*256];
      s  += v.x+v.y+v.z+v.w;
      ss += v.x*v.x+v.y*v.y+v.z*v.z+v.w*v.w;
    }
    s = wsum64(s); ss = wsum64(ss);
    __shared__ float r1[4], r2[4];
    if(lane==0){ r1[wid]=s; r2[wid]=ss; }
    __syncthreads();
    if(tid==0){
      ws[OFF_LNP + (b*16+seg)*2  ] = r1[0]+r1[1]+r1[2]+r1[3];
      ws[OFF_LNP + (b*16+seg)*2+1] = r2[0]+r2[1]+r2[2]+r2[3];
    }
  } else {
    int j = blk-128;                       // 4 blocks: prep M,u,v,c
    float mac[16], uac[16];
    #pragma unroll
    for(int r=0;r<16;r++){ mac[r]=0.f; uac[r]=0.f; }
    float vac=0.f, cac=0.f;
    for(int hk=0;hk<256;hk++){
      const float* wqrow = Wq + ((size_t)j*256+hk)*64;
      const float* wkrow = Wk + ((size_t)j*256+hk)*64;
      float wkl = wkrow[lane];
      float bkk = bk[j*256+hk], bqk = bq[j*256+hk];
      #pragma unroll
      for(int r=0;r<16;r++){ float wq=wqrow[wid*16+r]; mac[r]+=wq*wkl; uac[r]+=wq*bkk; }
      vac += bqk*wkl; cac += bqk*bkk;
    }
    #pragma unroll
    for(int r=0;r<16;r++) ws[OFF_M + j*4096+(wid*16+r)*64+lane] = mac[r]*SCALE;
    if(lane==0){
      #pragma unroll
      for(int r=0;r<16;r++) ws[OFF_U + j*64+wid*16+r] = uac[r]*SCALE;
    }
    if(wid==0) ws[OFF_V + j*64+lane] = vac*SCALE;
    if(tid==0) ws[OFF_C + j] = cac*SCALE;
  }
}

// ---------------- edge MLPs (round-2 proven body) ----------------
__global__ __launch_bounds__(256) void k_mlp(
    const float* __restrict__ kW1, const float* __restrict__ kb1,
    const float* __restrict__ kW2, const float* __restrict__ kb2,
    const float* __restrict__ fW1, const float* __restrict__ fb1,
    const float* __restrict__ fW2, const float* __restrict__ fb2,
    const float* __restrict__ ws, float* __restrict__ w_out, float* __restrict__ wf_out)
{
  int tid = threadIdx.x;
  int blk = blockIdx.x;                          // grid 8192
  int i = blk >> 3;
  int sub = blk & 7;
  int which = sub >> 2;                          // 0 = k-MLP, 1 = f-MLP
  int j = ((sub & 3) << 8) | tid;
  const float* W1 = which ? fW1 : kW1;
  const float* b1 = which ? fb1 : kb1;
  const float* W2 = which ? fW2 : kW2;
  const float* b2 = which ? fb2 : kb2;
  const float*  Ai = ws + (which ? OFF_AIF : OFF_AIK) + i*32;
  const float4* Bj = (const float4*)(ws + (which ? OFF_BJF : OFF_BJK) + j*32);
  float* outp = which ? wf_out : w_out;
  float h0[32];
  #pragma unroll
  for(int c4=0;c4<8;c4++){
    float4 v = Bj[c4];
    h0[c4*4+0]=lrelu(Ai[c4*4+0]+v.x);
    h0[c4*4+1]=lrelu(Ai[c4*4+1]+v.y);
    h0[c4*4+2]=lrelu(Ai[c4*4+2]+v.z);
    h0[c4*4+3]=lrelu(Ai[c4*4+3]+v.w);
  }
  float a = b2[0];
  #pragma unroll 4
  for(int o=0;o<64;o++){
    float sacc = b1[o];
    #pragma unroll
    for(int c=0;c<32;c++) sacc += W1[o*32+c]*h0[c];
    a += W2[o]*lrelu(sacc);
  }
  outp[i*1024+j] = a;
}

// ---------------- Gram of 64x64 LDS tiles ----------------
__device__ __forceinline__ void gram_tile(const float* sA, const float* sB,
    int wid, int lane, float* __restrict__ gp, float* __restrict__ gsp)
{
  float acc[16];
  #pragma unroll
  for(int q=0;q<16;q++) acc[q]=0.f;
  float gsa=0.f;
  for(int m=0;m<64;m++){
    const float4* cp = (const float4*)(sA + m*64 + wid*16);
    float bml = sB[m*64+lane];
    float4 a0=cp[0],a1=cp[1],a2=cp[2],a3=cp[3];
    acc[0]+=a0.x*bml; acc[1]+=a0.y*bml; acc[2]+=a0.z*bml; acc[3]+=a0.w*bml;
    acc[4]+=a1.x*bml; acc[5]+=a1.y*bml; acc[6]+=a1.z*bml; acc[7]+=a1.w*bml;
    acc[8]+=a2.x*bml; acc[9]+=a2.y*bml; acc[10]+=a2.z*bml; acc[11]+=a2.w*bml;
    acc[12]+=a3.x*bml; acc[13]+=a3.y*bml; acc[14]+=a3.z*bml; acc[15]+=a3.w*bml;
    gsa += bml;
  }
  #pragma unroll
  for(int q=0;q<16;q++) gp[(wid*16+q)*64+lane]=acc[q];
  if(wid==0) gsp[lane]=gsa;
}

// ---------------- T build from LDS Gram ----------------
__device__ __forceinline__ void build_T(const float* __restrict__ sG,
    const float* __restrict__ Mj, const float* __restrict__ uj,
    const float* __restrict__ vj, float cj, float gsl,
    int wid, int lane, float* __restrict__ sT, float* __restrict__ stv)
{
  float gv[64];
  #pragma unroll
  for(int c=0;c<64;c++) gv[c]=sG[c*64+lane];
  float tacc = cj*gsl;
  #pragma unroll
  for(int c=0;c<64;c++) tacc += vj[c]*gv[c];
  #pragma unroll
  for(int r=0;r<16;r++){
    const float* mrow = Mj + (wid*16+r)*64;       // wave-uniform -> s_load
    float acc = uj[wid*16+r]*gsl;
    #pragma unroll
    for(int c=0;c<64;c++) acc += mrow[c]*gv[c];
    sT[(wid*16+r)*64+lane]=acc;
  }
  if(wid==0) stv[lane]=tacc;
}

// ---------------- LN0 apply + Gram (round-2 proven body) ----------------
__global__ __launch_bounds__(256) void k_ln0ag(const float* __restrict__ xy,
    const float* __restrict__ g, const float* __restrict__ bb,
    const float* __restrict__ lnp,
    float* __restrict__ Vin, float* __restrict__ Gpart, float* __restrict__ gspart)
{
  __shared__ float sV[4096];
  int b = blockIdx.x>>5, ch = blockIdx.x&31;     // grid 256
  int tid = threadIdx.x, lane = tid&63;
  int wid = __builtin_amdgcn_readfirstlane(tid>>6);
  float s=0.f, ss=0.f;
  #pragma unroll
  for(int k2=0;k2<16;k2++){ s += lnp[(b*16+k2)*2]; ss += lnp[(b*16+k2)*2+1]; }
  float mean = s*(1.0f/131072.0f);
  float var  = ss*(1.0f/131072.0f) - mean*mean;
  float inv  = 1.0f/sqrtf(var+EPSC);
  const float4* x4 = (const float4*)(xy + ((size_t)b*2048 + ch*64)*64);
  const float4* g4 = (const float4*)(g  + (size_t)ch*4096);
  const float4* b4 = (const float4*)(bb + (size_t)ch*4096);
  float4* vo4 = (float4*)(Vin + ((size_t)b*2048 + ch*64)*64);
  float4* sv4 = (float4*)sV;
  for(int e=tid;e<1024;e+=256){
    float4 xv=x4[e], gv=g4[e], bv=b4[e];
    float4 r;
    r.x=(xv.x-mean)*inv*gv.x+bv.x;
    r.y=(xv.y-mean)*inv*gv.y+bv.y;
    r.z=(xv.z-mean)*inv*gv.z+bv.z;
    r.w=(xv.w-mean)*inv*gv.w+bv.w;
    vo4[e]=r; sv4[e]=r;
  }
  __syncthreads();
  gram_tile(sV, sV, wid, lane, Gpart+((size_t)(b*32+ch))*4096, gspart+(b*32+ch)*64);
}

// ---------------- layer: redundant G-reduce + T + mid + rowLN + residual + gram ----
__global__ __launch_bounds__(256) void k_layer(
    float* __restrict__ Vin, const float* __restrict__ xy,
    const float* __restrict__ Gsrc, const float* __restrict__ gssrc,
    float* __restrict__ Gdst, float* __restrict__ gsdst,
    const float* __restrict__ Mg, const float* __restrict__ ug,
    const float* __restrict__ vg, const float* __restrict__ cg,
    const float* __restrict__ lng, const float* __restrict__ lnb,
    int j, int cross)
{
  __shared__ float sV[4096];
  __shared__ float sT[4096];
  __shared__ float sG[4096];
  __shared__ float stv[64];
  int blk = blockIdx.x, tid = threadIdx.x;       // grid 256
  int lane = tid&63;
  int wid = __builtin_amdgcn_readfirstlane(tid>>6);
  int b = blk>>5, ch = blk&31;
  float* vbase = Vin + ((size_t)b*2048 + ch*64)*64;
  // stage Vin tile into LDS
  {
    const float4* vb4=(const float4*)vbase;
    float4* sv4=(float4*)sV;
    #pragma unroll
    for(int e=0;e<4;e++) sv4[tid+e*256]=vb4[tid+e*256];
  }
  // redundant reduce of 32 gram partials -> sG
  {
    float4 a0={0,0,0,0},a1={0,0,0,0},a2={0,0,0,0},a3={0,0,0,0};
    const float4* gp4 = (const float4*)(Gsrc + (size_t)b*32*4096) + tid*4;
    for(int c=0;c<32;c++){
      const float4* p = gp4 + c*1024;
      float4 v0=p[0],v1=p[1],v2=p[2],v3=p[3];
      a0.x+=v0.x;a0.y+=v0.y;a0.z+=v0.z;a0.w+=v0.w;
      a1.x+=v1.x;a1.y+=v1.y;a1.z+=v1.z;a1.w+=v1.w;
      a2.x+=v2.x;a2.y+=v2.y;a2.z+=v2.z;a2.w+=v2.w;
      a3.x+=v3.x;a3.y+=v3.y;a3.z+=v3.z;a3.w+=v3.w;
    }
    float4* sg4=(float4*)sG + tid*4;
    sg4[0]=a0; sg4[1]=a1; sg4[2]=a2; sg4[3]=a3;
  }
  float gsl=0.f;
  for(int c=0;c<32;c++) gsl += gssrc[(b*32+c)*64+lane];
  __syncthreads();
  build_T(sG, Mg+j*4096, ug+j*64, vg+j*64, cg[j], gsl, wid, lane, sT, stv);
  __syncthreads();
  // mid + rowLN + residual
  float Tcol[64];
  #pragma unroll
  for(int c=0;c<64;c++) Tcol[c]=sT[c*64+lane];
  float tvl=stv[lane];
  float gl=lng[j*64+lane], bl=lnb[j*64+lane];
  for(int rr=0;rr<16;rr++){
    int r=wid*16+rr;
    const float4* rp=(const float4*)(sV + r*64);
    float vold = sV[r*64+lane];
    float m=tvl;
    #pragma unroll
    for(int c4=0;c4<16;c4++){
      float4 vv=rp[c4];
      m += vv.x*Tcol[c4*4]+vv.y*Tcol[c4*4+1]+vv.z*Tcol[c4*4+2]+vv.w*Tcol[c4*4+3];
    }
    m*=DXDY;
    float mean=wsum64(m)*(1.f/64.f);
    float d=m-mean;
    float var=wsum64(d*d)*(1.f/64.f);
    float y=d*(1.f/sqrtf(var+EPSC))*gl+bl+vold;
    vbase[r*64+lane]=y;
    sV[r*64+lane]=y;
  }
  __syncthreads();
  if(!cross){
    gram_tile(sV, sV, wid, lane, Gdst+((size_t)(b*32+ch))*4096, gsdst+(b*32+ch)*64);
  } else if(ch<16){
    // cross-gram with xy (first 1024 tokens); reuse sG for the xy tile
    const float4* x4=(const float4*)(xy + ((size_t)b*2048+ch*64)*64);
    float4* sx4=(float4*)sG;
    #pragma unroll
    for(int e=0;e<4;e++) sx4[tid+e*256]=x4[tid+e*256];
    __syncthreads();
    gram_tile(sV, sG, wid, lane, Gdst+((size_t)(b*16+ch))*4096, gsdst+(b*16+ch)*64);
  }
}

// ---------------- P = weight^T@Vu + weightf^T@Vf (K-split 2) + colsums -------------
__global__ __launch_bounds__(256) void k_pw(const float* __restrict__ weight,
                                            const float* __restrict__ weightf,
                                            const float* __restrict__ Vin,
                                            float* __restrict__ Pg,
                                            float* __restrict__ wspart)
{
  int bid = blockIdx.x;                           // 512 = b(8) x jjc(32) x ns(2)
  int ns = bid&1, jjc=(bid>>1)&31, b = bid>>6;
  int lane = threadIdx.x&63;
  int wid = __builtin_amdgcn_readfirstlane(threadIdx.x>>6);
  int jj0 = jjc*32 + wid*8;
  const float* Vu = Vin + (size_t)b*131072;
  const float* Vf = Vu + 65536;
  float acc[8];
  #pragma unroll
  for(int q=0;q<8;q++) acc[q]=0.f;
  if(b==0){
    float cs[8];
    #pragma unroll
    for(int q=0;q<8;q++) cs[q]=0.f;
    for(int n=ns*512;n<ns*512+512;n++){
      float vu=Vu[n*64+lane], vf=Vf[n*64+lane];
      const float* wr  = weight  + n*1024 + jj0;
      const float* wfr = weightf + n*1024 + jj0;
      #pragma unroll
      for(int q=0;q<8;q++){ float wv=wr[q], fv=wfr[q]; acc[q]+=wv*vu+fv*vf; cs[q]+=wv+fv; }
    }
    if(lane==0){
      #pragma unroll
      for(int q=0;q<8;q++) wspart[ns*1024+jj0+q]=cs[q];
    }
  } else {
    for(int n=ns*512;n<ns*512+512;n++){
      float vu=Vu[n*64+lane], vf=Vf[n*64+lane];
      const float* wr  = weight  + n*1024 + jj0;
      const float* wfr = weightf + n*1024 + jj0;
      #pragma unroll
      for(int q=0;q<8;q++){ acc[q]+=wr[q]*vu+wfr[q]*vf; }
    }
  }
  float* pp = Pg + ((size_t)(b*2+ns)*1024 + jj0)*64;
  #pragma unroll
  for(int q=0;q<8;q++) pp[q*64+lane]=acc[q];
}

// ---------------- final: redundant T3 build + out ----------------
__global__ __launch_bounds__(256) void k_final(
    const float* __restrict__ Gp2, const float* __restrict__ gsp2,
    const float* __restrict__ Mg, const float* __restrict__ ug,
    const float* __restrict__ vg, const float* __restrict__ cg,
    const float* __restrict__ Pg, const float* __restrict__ wspart,
    float* __restrict__ out)
{
  __shared__ float sG[4096];
  __shared__ float sT[4096];
  __shared__ float stv[64];
  int blk = blockIdx.x, tid = threadIdx.x;       // grid 256
  int lane = tid&63;
  int wid = __builtin_amdgcn_readfirstlane(tid>>6);
  int b = blk>>5, rg = blk&31;
  {
    float4 a0={0,0,0,0},a1={0,0,0,0},a2={0,0,0,0},a3={0,0,0,0};
    const float4* gp4 = (const float4*)(Gp2 + (size_t)b*16*4096) + tid*4;
    for(int c=0;c<16;c++){
      const float4* p = gp4 + c*1024;
      float4 v0=p[0],v1=p[1],v2=p[2],v3=p[3];
      a0.x+=v0.x;a0.y+=v0.y;a0.z+=v0.z;a0.w+=v0.w;
      a1.x+=v1.x;a1.y+=v1.y;a1.z+=v1.z;a1.w+=v1.w;
      a2.x+=v2.x;a2.y+=v2.y;a2.z+=v2.z;a2.w+=v2.w;
      a3.x+=v3.x;a3.y+=v3.y;a3.z+=v3.z;a3.w+=v3.w;
    }
    float4* sg4=(float4*)sG + tid*4;
    sg4[0]=a0; sg4[1]=a1; sg4[2]=a2; sg4[3]=a3;
  }
  float gsl=0.f;
  for(int c=0;c<16;c++) gsl += gsp2[(b*16+c)*64+lane];
  __syncthreads();
  build_T(sG, Mg+3*4096, ug+3*64, vg+3*64, cg[3], gsl, wid, lane, sT, stv);
  __syncthreads();
  float Tcol[64];
  #pragma unroll
  for(int c=0;c<64;c++) Tcol[c]=sT[c*64+lane];
  float t3l=stv[lane];
  for(int rw=0;rw<8;rw++){
    int jj=rg*32+wid*8+rw;
    float p = Pg[((size_t)(b*2+0)*1024+jj)*64+lane]
            + Pg[((size_t)(b*2+1)*1024+jj)*64+lane];
    float wsm = wspart[jj] + wspart[1024+jj];
    float acc=wsm*t3l;
    #pragma unroll
    for(int c=0;c<64;c++) acc += __shfl(p,c)*Tcol[c];
    out[((size_t)(b*1024)+jj)*64+lane]=acc*(DXDY*DXDY);
  }
}

extern "C" void kernel_launch(void* const* d_in, const int* in_sizes, int n_in,
                              void* d_out, int out_size, void* d_ws, size_t ws_size,
                              hipStream_t stream)
{
  (void)in_sizes; (void)n_in; (void)out_size; (void)ws_size;
  const float* xy   = (const float*)d_in[0];
  const float* kW0  = (const float*)d_in[1];
  const float* kb0  = (const float*)d_in[2];
  const float* kW1  = (const float*)d_in[3];
  const float* kb1  = (const float*)d_in[4];
  const float* kW2  = (const float*)d_in[5];
  const float* kb2  = (const float*)d_in[6];
  const float* fW0  = (const float*)d_in[7];
  const float* fb0  = (const float*)d_in[8];
  const float* fW1  = (const float*)d_in[9];
  const float* fb1  = (const float*)d_in[10];
  const float* fW2  = (const float*)d_in[11];
  const float* fb2  = (const float*)d_in[12];
  const float* Wq   = (const float*)d_in[13];
  const float* bq   = (const float*)d_in[14];
  const float* Wk   = (const float*)d_in[15];
  const float* bk   = (const float*)d_in[16];
  const float* ln0g = (const float*)d_in[17];
  const float* ln0b = (const float*)d_in[18];
  const float* lng  = (const float*)d_in[19];
  const float* lnb  = (const float*)d_in[20];
  float* out = (float*)d_out;
  float* ws  = (float*)d_ws;

  float* lnp    = ws+OFF_LNP;
  float* Mg     = ws+OFF_M;
  float* ug     = ws+OFF_U;
  float* vg     = ws+OFF_V;
  float* cg     = ws+OFF_C;
  float* wspart = ws+OFF_WSPART;
  float* Vin    = ws+OFF_VIN;
  float* weight = ws+OFF_W;
  float* weightf= ws+OFF_WF;
  float* GPA    = ws+OFF_GPA;
  float* GSA    = ws+OFF_GSA;
  float* GPB    = ws+OFF_GPB;
  float* GSB    = ws+OFF_GSB;
  float* Pg     = ws+OFF_P;

  k_pre0<<<132, 256, 0, stream>>>(kW0,kb0,fW0,fb0, xy, Wq,bq,Wk,bk, ws);
  k_mlp<<<8192, 256, 0, stream>>>(kW1,kb1,kW2,kb2, fW1,fb1,fW2,fb2,
                                  ws, weight, weightf);
  k_ln0ag<<<256, 256, 0, stream>>>(xy, ln0g, ln0b, lnp, Vin, GPA, GSA);

  k_layer<<<256, 256, 0, stream>>>(Vin, xy, GPA, GSA, GPB, GSB,
                                   Mg, ug, vg, cg, lng, lnb, 0, 0);
  k_layer<<<256, 256, 0, stream>>>(Vin, xy, GPB, GSB, GPA, GSA,
                                   Mg, ug, vg, cg, lng, lnb, 1, 0);
  k_layer<<<256, 256, 0, stream>>>(Vin, xy, GPA, GSA, GPB, GSB,
                                   Mg, ug, vg, cg, lng, lnb, 2, 1);

  k_pw<<<512, 256, 0, stream>>>(weight, weightf, Vin, Pg, wspart);
  k_final<<<256, 256, 0, stream>>>(GPB, GSB, Mg, ug, vg, cg, Pg, wspart, out);
}

// Round 5
// 350.346 us; speedup vs baseline: 2.4105x; 1.2543x over previous
//
#include <hip/hip_runtime.h>
#include <math.h>

#define BATCH 8
constexpr float DXC   = 2.0f/31.0f;
constexpr float DXDY  = DXC*DXC;
constexpr float SCALE = 0.125f;      // 1/sqrt(64), folded into M/u/v/c
constexpr float EPSC  = 1e-5f;
constexpr float SLOPEC= 0.01f;

// ---- workspace float offsets ----
#define OFF_LNP    0u         // 256
#define OFF_M      256u       // 16384
#define OFF_U      16640u     // 256
#define OFF_V      16896u     // 256
#define OFF_C      17152u     // 16
#define OFF_WSPART 17168u     // 2048 (2 ns-partials x 1024)
#define OFF_VIN    150288u    // 1048576
#define OFF_W      1198864u   // 1048576
#define OFF_WF     2247440u   // 1048576
#define OFF_GPA    3296016u   // 1048576  (gram partials, buffer A)
#define OFF_GSA    4344592u   // 16384
#define OFF_GPB    4360976u   // 1048576  (buffer B; also holds final cross-gram)
#define OFF_GSB    5409552u   // 16384
#define OFF_P      5425936u   // 1048576  (2 ns-partials x 8b x 1024jj x 64f)

typedef short bf16x8 __attribute__((ext_vector_type(8)));
typedef float f32x4  __attribute__((ext_vector_type(4)));

__device__ __forceinline__ unsigned cvt2bf(float a, float b){
  unsigned r; asm("v_cvt_pk_bf16_f32 %0, %1, %2" : "=v"(r) : "v"(a), "v"(b)); return r;
}

__device__ __forceinline__ float lrelu(float x){ return fmaxf(x, SLOPEC*x); }

__device__ __forceinline__ float wsum64(float v){
  #pragma unroll
  for(int off=32; off; off>>=1) v += __shfl_xor(v, off);
  return v;
}

// ========== fused: edge MLPs via bf16 MFMA  |  LN0 partials  |  M/u/v/c prep ==========
__global__ __launch_bounds__(256) void k_mlp(
    const float* __restrict__ kW0, const float* __restrict__ kb0,
    const float* __restrict__ kW1, const float* __restrict__ kb1,
    const float* __restrict__ kW2, const float* __restrict__ kb2,
    const float* __restrict__ fW0, const float* __restrict__ fb0,
    const float* __restrict__ fW1, const float* __restrict__ fb1,
    const float* __restrict__ fW2, const float* __restrict__ fb2,
    const float* __restrict__ xy,
    const float* __restrict__ Wq, const float* __restrict__ bq,
    const float* __restrict__ Wk, const float* __restrict__ bk,
    float* __restrict__ ws, float* __restrict__ w_out, float* __restrict__ wf_out)
{
  __shared__ unsigned Hlds[16384];   // H bf16: [kg][1024 j][4 u32] = 64 KB
  __shared__ unsigned W1lds[1024];   // W1 bf16: [64 o][16 u32] = 4 KB
  int blk = blockIdx.x, tid = threadIdx.x;
  int lane = tid&63;
  int wid = __builtin_amdgcn_readfirstlane(tid>>6);

  if(blk < 2048){
    // ---------------- edge MLP for (which, i), all 1024 j ----------------
    int which = blk>>10, i = blk&1023;
    const float* W0 = which? fW0:kW0; const float* b0 = which? fb0:kb0;
    const float* W1 = which? fW1:kW1; const float* b1 = which? fb1:kb1;
    const float* W2 = which? fW2:kW2; const float* b2 = which? fb2:kb2;
    float* outp = which? wf_out : w_out;
    // W1 -> bf16 LDS (row-major [o][c])
    {
      const float* src = W1 + tid*8;
      uint4 p;
      p.x=cvt2bf(src[0],src[1]); p.y=cvt2bf(src[2],src[3]);
      p.z=cvt2bf(src[4],src[5]); p.w=cvt2bf(src[6],src[7]);
      *(uint4*)&W1lds[tid*4] = p;
    }
    // H build: H[j][c] = lrelu(Ai[c] + W0[c][2]*xj + W0[c][3]*yj + b0[c])
    float xi = -1.f + DXC*(float)(i>>5), yi = -1.f + DXC*(float)(i&31);
    float a0s[32];
    #pragma unroll
    for(int c=0;c<32;c++) a0s[c] = W0[c*4+0]*xi + W0[c*4+1]*yi + b0[c];
    #pragma unroll
    for(int rep=0;rep<4;rep++){
      int j = rep*256 + tid;
      float xj = -1.f + DXC*(float)(j>>5), yj = -1.f + DXC*(float)(j&31);
      #pragma unroll
      for(int kg=0;kg<4;kg++){
        float h[8];
        #pragma unroll
        for(int t=0;t<8;t++){
          int c = kg*8+t;
          float p = a0s[c] + W0[c*4+2]*xj + W0[c*4+3]*yj;
          h[t] = fmaxf(p, SLOPEC*p);
        }
        uint4 hp;
        hp.x=cvt2bf(h[0],h[1]); hp.y=cvt2bf(h[2],h[3]);
        hp.z=cvt2bf(h[4],h[5]); hp.w=cvt2bf(h[6],h[7]);
        *(uint4*)&Hlds[(kg*1024+j)*4] = hp;
      }
    }
    // per-lane o metadata: o = ot*16 + grp*4 + r
    int grp = lane>>4;
    float b1v[16], w2v[16];
    #pragma unroll
    for(int ot=0;ot<4;ot++){
      #pragma unroll
      for(int r=0;r<4;r++){
        int o = ot*16 + grp*4 + r;
        b1v[ot*4+r] = b1[o];
        w2v[ot*4+r] = W2[o];
      }
    }
    float b2s = b2[0];
    __syncthreads();
    // A-frags: lane holds W1[ot*16+(lane&15)][grp*8 .. +7]
    bf16x8 afr[4];
    #pragma unroll
    for(int ot=0;ot<4;ot++)
      afr[ot] = *(const bf16x8*)&W1lds[(ot*16 + (lane&15))*16 + grp*4];
    int jbase = wid*256;
    f32x4 zz = {0.f,0.f,0.f,0.f};
    for(int jt=0;jt<16;jt++){
      int j0 = jbase + jt*16;
      // B-frag: lane holds H[j0+(lane&15)][grp*8 .. +7]
      bf16x8 bfr = *(const bf16x8*)&Hlds[(grp*1024 + j0 + (lane&15))*4];
      f32x4 d0 = __builtin_amdgcn_mfma_f32_16x16x32_bf16(afr[0], bfr, zz, 0,0,0);
      f32x4 d1 = __builtin_amdgcn_mfma_f32_16x16x32_bf16(afr[1], bfr, zz, 0,0,0);
      f32x4 d2 = __builtin_amdgcn_mfma_f32_16x16x32_bf16(afr[2], bfr, zz, 0,0,0);
      f32x4 d3 = __builtin_amdgcn_mfma_f32_16x16x32_bf16(afr[3], bfr, zz, 0,0,0);
      float part = 0.f;
      #pragma unroll
      for(int r=0;r<4;r++){
        float s0 = d0[r]+b1v[r];    part = fmaf(w2v[r],    fmaxf(s0,SLOPEC*s0), part);
        float s1 = d1[r]+b1v[4+r];  part = fmaf(w2v[4+r],  fmaxf(s1,SLOPEC*s1), part);
        float s2 = d2[r]+b1v[8+r];  part = fmaf(w2v[8+r],  fmaxf(s2,SLOPEC*s2), part);
        float s3 = d3[r]+b1v[12+r]; part = fmaf(w2v[12+r], fmaxf(s3,SLOPEC*s3), part);
      }
      part += __shfl_xor(part, 16);
      part += __shfl_xor(part, 32);
      if(lane<16) outp[i*1024 + j0 + lane] = part + b2s;
    }
  } else if(blk < 2176){
    // ---------------- LN0 partial sums (128 blocks) ----------------
    int bb = blk-2048;
    int b = bb>>4, seg = bb&15;
    const float4* x4 = (const float4*)(xy + (size_t)b*131072 + seg*8192);
    float s=0.f, ss=0.f;
    #pragma unroll
    for(int k2=0;k2<8;k2++){
      float4 v = x4[tid + k2*256];
      s  += v.x+v.y+v.z+v.w;
      ss += v.x*v.x+v.y*v.y+v.z*v.z+v.w*v.w;
    }
    s = wsum64(s); ss = wsum64(ss);
    float* red = (float*)Hlds;
    if(lane==0){ red[wid]=s; red[4+wid]=ss; }
    __syncthreads();
    if(tid==0){
      ws[OFF_LNP + (b*16+seg)*2  ] = red[0]+red[1]+red[2]+red[3];
      ws[OFF_LNP + (b*16+seg)*2+1] = red[4]+red[5]+red[6]+red[7];
    }
  } else {
    // ---------------- prep M,u,v,c (4 blocks) ----------------
    int j = blk-2176;
    float mac[16], uac[16];
    #pragma unroll
    for(int r=0;r<16;r++){ mac[r]=0.f; uac[r]=0.f; }
    float vac=0.f, cac=0.f;
    for(int hk=0;hk<256;hk++){
      const float* wqrow = Wq + ((size_t)j*256+hk)*64;
      const float* wkrow = Wk + ((size_t)j*256+hk)*64;
      float wkl = wkrow[lane];
      float bkk = bk[j*256+hk], bqk = bq[j*256+hk];
      #pragma unroll
      for(int r=0;r<16;r++){ float wq=wqrow[wid*16+r]; mac[r]+=wq*wkl; uac[r]+=wq*bkk; }
      vac += bqk*wkl; cac += bqk*bkk;
    }
    #pragma unroll
    for(int r=0;r<16;r++) ws[OFF_M + j*4096+(wid*16+r)*64+lane] = mac[r]*SCALE;
    if(lane==0){
      #pragma unroll
      for(int r=0;r<16;r++) ws[OFF_U + j*64+wid*16+r] = uac[r]*SCALE;
    }
    if(wid==0) ws[OFF_V + j*64+lane] = vac*SCALE;
    if(tid==0) ws[OFF_C + j] = cac*SCALE;
  }
}

// ---------------- Gram of 64x64 LDS tiles ----------------
__device__ __forceinline__ void gram_tile(const float* sA, const float* sB,
    int wid, int lane, float* __restrict__ gp, float* __restrict__ gsp)
{
  float acc[16];
  #pragma unroll
  for(int q=0;q<16;q++) acc[q]=0.f;
  float gsa=0.f;
  for(int m=0;m<64;m++){
    const float4* cp = (const float4*)(sA + m*64 + wid*16);
    float bml = sB[m*64+lane];
    float4 a0=cp[0],a1=cp[1],a2=cp[2],a3=cp[3];
    acc[0]+=a0.x*bml; acc[1]+=a0.y*bml; acc[2]+=a0.z*bml; acc[3]+=a0.w*bml;
    acc[4]+=a1.x*bml; acc[5]+=a1.y*bml; acc[6]+=a1.z*bml; acc[7]+=a1.w*bml;
    acc[8]+=a2.x*bml; acc[9]+=a2.y*bml; acc[10]+=a2.z*bml; acc[11]+=a2.w*bml;
    acc[12]+=a3.x*bml; acc[13]+=a3.y*bml; acc[14]+=a3.z*bml; acc[15]+=a3.w*bml;
    gsa += bml;
  }
  #pragma unroll
  for(int q=0;q<16;q++) gp[(wid*16+q)*64+lane]=acc[q];
  if(wid==0) gsp[lane]=gsa;
}

// ---------------- T build from LDS Gram ----------------
__device__ __forceinline__ void build_T(const float* __restrict__ sG,
    const float* __restrict__ Mj, const float* __restrict__ uj,
    const float* __restrict__ vj, float cj, float gsl,
    int wid, int lane, float* __restrict__ sT, float* __restrict__ stv)
{
  float gv[64];
  #pragma unroll
  for(int c=0;c<64;c++) gv[c]=sG[c*64+lane];
  float tacc = cj*gsl;
  #pragma unroll
  for(int c=0;c<64;c++) tacc += vj[c]*gv[c];
  #pragma unroll
  for(int r=0;r<16;r++){
    const float* mrow = Mj + (wid*16+r)*64;       // wave-uniform -> s_load
    float acc = uj[wid*16+r]*gsl;
    #pragma unroll
    for(int c=0;c<64;c++) acc += mrow[c]*gv[c];
    sT[(wid*16+r)*64+lane]=acc;
  }
  if(wid==0) stv[lane]=tacc;
}

// ---------------- LN0 apply + Gram ----------------
__global__ __launch_bounds__(256) void k_ln0ag(const float* __restrict__ xy,
    const float* __restrict__ g, const float* __restrict__ bb,
    const float* __restrict__ lnp,
    float* __restrict__ Vin, float* __restrict__ Gpart, float* __restrict__ gspart)
{
  __shared__ float sV[4096];
  int b = blockIdx.x>>5, ch = blockIdx.x&31;     // grid 256
  int tid = threadIdx.x, lane = tid&63;
  int wid = __builtin_amdgcn_readfirstlane(tid>>6);
  float s=0.f, ss=0.f;
  #pragma unroll
  for(int k2=0;k2<16;k2++){ s += lnp[(b*16+k2)*2]; ss += lnp[(b*16+k2)*2+1]; }
  float mean = s*(1.0f/131072.0f);
  float var  = ss*(1.0f/131072.0f) - mean*mean;
  float inv  = 1.0f/sqrtf(var+EPSC);
  const float4* x4 = (const float4*)(xy + ((size_t)b*2048 + ch*64)*64);
  const float4* g4 = (const float4*)(g  + (size_t)ch*4096);
  const float4* b4 = (const float4*)(bb + (size_t)ch*4096);
  float4* vo4 = (float4*)(Vin + ((size_t)b*2048 + ch*64)*64);
  float4* sv4 = (float4*)sV;
  for(int e=tid;e<1024;e+=256){
    float4 xv=x4[e], gv=g4[e], bv=b4[e];
    float4 r;
    r.x=(xv.x-mean)*inv*gv.x+bv.x;
    r.y=(xv.y-mean)*inv*gv.y+bv.y;
    r.z=(xv.z-mean)*inv*gv.z+bv.z;
    r.w=(xv.w-mean)*inv*gv.w+bv.w;
    vo4[e]=r; sv4[e]=r;
  }
  __syncthreads();
  gram_tile(sV, sV, wid, lane, Gpart+((size_t)(b*32+ch))*4096, gspart+(b*32+ch)*64);
}

// ---------------- layer: redundant G-reduce + T + mid + rowLN + residual + gram ----
__global__ __launch_bounds__(256) void k_layer(
    float* __restrict__ Vin, const float* __restrict__ xy,
    const float* __restrict__ Gsrc, const float* __restrict__ gssrc,
    float* __restrict__ Gdst, float* __restrict__ gsdst,
    const float* __restrict__ Mg, const float* __restrict__ ug,
    const float* __restrict__ vg, const float* __restrict__ cg,
    const float* __restrict__ lng, const float* __restrict__ lnb,
    int j, int cross)
{
  __shared__ float sV[4096];
  __shared__ float sT[4096];
  __shared__ float sG[4096];
  __shared__ float stv[64];
  int blk = blockIdx.x, tid = threadIdx.x;       // grid 256
  int lane = tid&63;
  int wid = __builtin_amdgcn_readfirstlane(tid>>6);
  int b = blk>>5, ch = blk&31;
  float* vbase = Vin + ((size_t)b*2048 + ch*64)*64;
  {
    const float4* vb4=(const float4*)vbase;
    float4* sv4=(float4*)sV;
    #pragma unroll
    for(int e=0;e<4;e++) sv4[tid+e*256]=vb4[tid+e*256];
  }
  {
    float4 a0={0,0,0,0},a1={0,0,0,0},a2={0,0,0,0},a3={0,0,0,0};
    const float4* gp4 = (const float4*)(Gsrc + (size_t)b*32*4096) + tid*4;
    for(int c=0;c<32;c++){
      const float4* p = gp4 + c*1024;
      float4 v0=p[0],v1=p[1],v2=p[2],v3=p[3];
      a0.x+=v0.x;a0.y+=v0.y;a0.z+=v0.z;a0.w+=v0.w;
      a1.x+=v1.x;a1.y+=v1.y;a1.z+=v1.z;a1.w+=v1.w;
      a2.x+=v2.x;a2.y+=v2.y;a2.z+=v2.z;a2.w+=v2.w;
      a3.x+=v3.x;a3.y+=v3.y;a3.z+=v3.z;a3.w+=v3.w;
    }
    float4* sg4=(float4*)sG + tid*4;
    sg4[0]=a0; sg4[1]=a1; sg4[2]=a2; sg4[3]=a3;
  }
  float gsl=0.f;
  for(int c=0;c<32;c++) gsl += gssrc[(b*32+c)*64+lane];
  __syncthreads();
  build_T(sG, Mg+j*4096, ug+j*64, vg+j*64, cg[j], gsl, wid, lane, sT, stv);
  __syncthreads();
  float Tcol[64];
  #pragma unroll
  for(int c=0;c<64;c++) Tcol[c]=sT[c*64+lane];
  float tvl=stv[lane];
  float gl=lng[j*64+lane], bl=lnb[j*64+lane];
  for(int rr=0;rr<16;rr++){
    int r=wid*16+rr;
    const float4* rp=(const float4*)(sV + r*64);
    float vold = sV[r*64+lane];
    float m=tvl;
    #pragma unroll
    for(int c4=0;c4<16;c4++){
      float4 vv=rp[c4];
      m += vv.x*Tcol[c4*4]+vv.y*Tcol[c4*4+1]+vv.z*Tcol[c4*4+2]+vv.w*Tcol[c4*4+3];
    }
    m*=DXDY;
    float mean=wsum64(m)*(1.f/64.f);
    float d=m-mean;
    float var=wsum64(d*d)*(1.f/64.f);
    float y=d*(1.f/sqrtf(var+EPSC))*gl+bl+vold;
    vbase[r*64+lane]=y;
    sV[r*64+lane]=y;
  }
  __syncthreads();
  if(!cross){
    gram_tile(sV, sV, wid, lane, Gdst+((size_t)(b*32+ch))*4096, gsdst+(b*32+ch)*64);
  } else if(ch<16){
    const float4* x4=(const float4*)(xy + ((size_t)b*2048+ch*64)*64);
    float4* sx4=(float4*)sG;
    #pragma unroll
    for(int e=0;e<4;e++) sx4[tid+e*256]=x4[tid+e*256];
    __syncthreads();
    gram_tile(sV, sG, wid, lane, Gdst+((size_t)(b*16+ch))*4096, gsdst+(b*16+ch)*64);
  }
}

// ---------------- P = weight^T@Vu + weightf^T@Vf (K-split 2) + colsums -------------
__global__ __launch_bounds__(256) void k_pw(const float* __restrict__ weight,
                                            const float* __restrict__ weightf,
                                            const float* __restrict__ Vin,
                                            float* __restrict__ Pg,
                                            float* __restrict__ wspart)
{
  int bid = blockIdx.x;                           // 512 = b(8) x jjc(32) x ns(2)
  int ns = bid&1, jjc=(bid>>1)&31, b = bid>>6;
  int lane = threadIdx.x&63;
  int wid = __builtin_amdgcn_readfirstlane(threadIdx.x>>6);
  int jj0 = jjc*32 + wid*8;
  const float* Vu = Vin + (size_t)b*131072;
  const float* Vf = Vu + 65536;
  float acc[8];
  #pragma unroll
  for(int q=0;q<8;q++) acc[q]=0.f;
  if(b==0){
    float cs[8];
    #pragma unroll
    for(int q=0;q<8;q++) cs[q]=0.f;
    for(int n=ns*512;n<ns*512+512;n++){
      float vu=Vu[n*64+lane], vf=Vf[n*64+lane];
      const float* wr  = weight  + n*1024 + jj0;
      const float* wfr = weightf + n*1024 + jj0;
      #pragma unroll
      for(int q=0;q<8;q++){ float wv=wr[q], fv=wfr[q]; acc[q]+=wv*vu+fv*vf; cs[q]+=wv+fv; }
    }
    if(lane==0){
      #pragma unroll
      for(int q=0;q<8;q++) wspart[ns*1024+jj0+q]=cs[q];
    }
  } else {
    for(int n=ns*512;n<ns*512+512;n++){
      float vu=Vu[n*64+lane], vf=Vf[n*64+lane];
      const float* wr  = weight  + n*1024 + jj0;
      const float* wfr = weightf + n*1024 + jj0;
      #pragma unroll
      for(int q=0;q<8;q++){ acc[q]+=wr[q]*vu+wfr[q]*vf; }
    }
  }
  float* pp = Pg + ((size_t)(b*2+ns)*1024 + jj0)*64;
  #pragma unroll
  for(int q=0;q<8;q++) pp[q*64+lane]=acc[q];
}

// ---------------- final: redundant T3 build + out ----------------
__global__ __launch_bounds__(256) void k_final(
    const float* __restrict__ Gp2, const float* __restrict__ gsp2,
    const float* __restrict__ Mg, const float* __restrict__ ug,
    const float* __restrict__ vg, const float* __restrict__ cg,
    const float* __restrict__ Pg, const float* __restrict__ wspart,
    float* __restrict__ out)
{
  __shared__ float sG[4096];
  __shared__ float sT[4096];
  __shared__ float stv[64];
  int blk = blockIdx.x, tid = threadIdx.x;       // grid 256
  int lane = tid&63;
  int wid = __builtin_amdgcn_readfirstlane(tid>>6);
  int b = blk>>5, rg = blk&31;
  {
    float4 a0={0,0,0,0},a1={0,0,0,0},a2={0,0,0,0},a3={0,0,0,0};
    const float4* gp4 = (const float4*)(Gp2 + (size_t)b*16*4096) + tid*4;
    for(int c=0;c<16;c++){
      const float4* p = gp4 + c*1024;
      float4 v0=p[0],v1=p[1],v2=p[2],v3=p[3];
      a0.x+=v0.x;a0.y+=v0.y;a0.z+=v0.z;a0.w+=v0.w;
      a1.x+=v1.x;a1.y+=v1.y;a1.z+=v1.z;a1.w+=v1.w;
      a2.x+=v2.x;a2.y+=v2.y;a2.z+=v2.z;a2.w+=v2.w;
      a3.x+=v3.x;a3.y+=v3.y;a3.z+=v3.z;a3.w+=v3.w;
    }
    float4* sg4=(float4*)sG + tid*4;
    sg4[0]=a0; sg4[1]=a1; sg4[2]=a2; sg4[3]=a3;
  }
  float gsl=0.f;
  for(int c=0;c<16;c++) gsl += gsp2[(b*16+c)*64+lane];
  __syncthreads();
  build_T(sG, Mg+3*4096, ug+3*64, vg+3*64, cg[3], gsl, wid, lane, sT, stv);
  __syncthreads();
  float Tcol[64];
  #pragma unroll
  for(int c=0;c<64;c++) Tcol[c]=sT[c*64+lane];
  float t3l=stv[lane];
  for(int rw=0;rw<8;rw++){
    int jj=rg*32+wid*8+rw;
    float p = Pg[((size_t)(b*2+0)*1024+jj)*64+lane]
            + Pg[((size_t)(b*2+1)*1024+jj)*64+lane];
    float wsm = wspart[jj] + wspart[1024+jj];
    float acc=wsm*t3l;
    #pragma unroll
    for(int c=0;c<64;c++) acc += __shfl(p,c)*Tcol[c];
    out[((size_t)(b*1024)+jj)*64+lane]=acc*(DXDY*DXDY);
  }
}

extern "C" void kernel_launch(void* const* d_in, const int* in_sizes, int n_in,
                              void* d_out, int out_size, void* d_ws, size_t ws_size,
                              hipStream_t stream)
{
  (void)in_sizes; (void)n_in; (void)out_size; (void)ws_size;
  const float* xy   = (const float*)d_in[0];
  const float* kW0  = (const float*)d_in[1];
  const float* kb0  = (const float*)d_in[2];
  const float* kW1  = (const float*)d_in[3];
  const float* kb1  = (const float*)d_in[4];
  const float* kW2  = (const float*)d_in[5];
  const float* kb2  = (const float*)d_in[6];
  const float* fW0  = (const float*)d_in[7];
  const float* fb0  = (const float*)d_in[8];
  const float* fW1  = (const float*)d_in[9];
  const float* fb1  = (const float*)d_in[10];
  const float* fW2  = (const float*)d_in[11];
  const float* fb2  = (const float*)d_in[12];
  const float* Wq   = (const float*)d_in[13];
  const float* bq   = (const float*)d_in[14];
  const float* Wk   = (const float*)d_in[15];
  const float* bk   = (const float*)d_in[16];
  const float* ln0g = (const float*)d_in[17];
  const float* ln0b = (const float*)d_in[18];
  const float* lng  = (const float*)d_in[19];
  const float* lnb  = (const float*)d_in[20];
  float* out = (float*)d_out;
  float* ws  = (float*)d_ws;

  float* lnp    = ws+OFF_LNP;
  float* Mg     = ws+OFF_M;
  float* ug     = ws+OFF_U;
  float* vg     = ws+OFF_V;
  float* cg     = ws+OFF_C;
  float* wspart = ws+OFF_WSPART;
  float* Vin    = ws+OFF_VIN;
  float* weight = ws+OFF_W;
  float* weightf= ws+OFF_WF;
  float* GPA    = ws+OFF_GPA;
  float* GSA    = ws+OFF_GSA;
  float* GPB    = ws+OFF_GPB;
  float* GSB    = ws+OFF_GSB;
  float* Pg     = ws+OFF_P;

  k_mlp<<<2180, 256, 0, stream>>>(kW0,kb0,kW1,kb1,kW2,kb2,
                                  fW0,fb0,fW1,fb1,fW2,fb2,
                                  xy, Wq,bq,Wk,bk, ws, weight, weightf);
  k_ln0ag<<<256, 256, 0, stream>>>(xy, ln0g, ln0b, lnp, Vin, GPA, GSA);

  k_layer<<<256, 256, 0, stream>>>(Vin, xy, GPA, GSA, GPB, GSB,
                                   Mg, ug, vg, cg, lng, lnb, 0, 0);
  k_layer<<<256, 256, 0, stream>>>(Vin, xy, GPB, GSB, GPA, GSA,
                                   Mg, ug, vg, cg, lng, lnb, 1, 0);
  k_layer<<<256, 256, 0, stream>>>(Vin, xy, GPA, GSA, GPB, GSB,
                                   Mg, ug, vg, cg, lng, lnb, 2, 1);

  k_pw<<<512, 256, 0, stream>>>(weight, weightf, Vin, Pg, wspart);
  k_final<<<256, 256, 0, stream>>>(GPB, GSB, Mg, ug, vg, cg, Pg, wspart, out);
}

// Round 6
// 339.731 us; speedup vs baseline: 2.4859x; 1.0312x over previous
//
#include <hip/hip_runtime.h>
#include <math.h>

#define BATCH 8
constexpr float DXC   = 2.0f/31.0f;
constexpr float DXDY  = DXC*DXC;
constexpr float SCALE = 0.125f;      // 1/sqrt(64), folded into M/u/v/c
constexpr float EPSC  = 1e-5f;
constexpr float SLOPEC= 0.01f;

// ---- workspace float offsets ----
#define OFF_LNP    0u         // 256
#define OFF_M      256u       // 16384
#define OFF_U      16640u     // 256
#define OFF_V      16896u     // 256
#define OFF_C      17152u     // 16
#define OFF_WSPART 17168u     // 2048 (2 ns-partials x 1024)
#define OFF_VIN    150288u    // 1048576
#define OFF_W      1198864u   // 1048576
#define OFF_WF     2247440u   // 1048576
#define OFF_GPA    3296016u   // 1048576  (gram partials, buffer A)
#define OFF_GSA    4344592u   // 16384
#define OFF_GPB    4360976u   // 1048576  (buffer B; also holds final cross-gram)
#define OFF_GSB    5409552u   // 16384
#define OFF_P      5425936u   // 1048576  (2 ns-partials x 8b x 1024jj x 64f)

typedef short bf16x8 __attribute__((ext_vector_type(8)));
typedef float f32x4  __attribute__((ext_vector_type(4)));

__device__ __forceinline__ unsigned cvt2bf(float a, float b){
  unsigned r; asm("v_cvt_pk_bf16_f32 %0, %1, %2" : "=v"(r) : "v"(a), "v"(b)); return r;
}

__device__ __forceinline__ float lrelu(float x){ return fmaxf(x, SLOPEC*x); }

__device__ __forceinline__ float wsum64(float v){
  #pragma unroll
  for(int off=32; off; off>>=1) v += __shfl_xor(v, off);
  return v;
}

// ========== fused: edge MLPs (bf16 MFMA, 256-j chunks) | LN0 partials | prep ==========
// LDS ~20 KB -> ~7 blocks/CU (vs 68 KB / 2 blocks in round 5).
__global__ __launch_bounds__(256) void k_mlp(
    const float* __restrict__ kW0, const float* __restrict__ kb0,
    const float* __restrict__ kW1, const float* __restrict__ kb1,
    const float* __restrict__ kW2, const float* __restrict__ kb2,
    const float* __restrict__ fW0, const float* __restrict__ fb0,
    const float* __restrict__ fW1, const float* __restrict__ fb1,
    const float* __restrict__ fW2, const float* __restrict__ fb2,
    const float* __restrict__ xy,
    const float* __restrict__ Wq, const float* __restrict__ bq,
    const float* __restrict__ Wk, const float* __restrict__ bk,
    float* __restrict__ ws, float* __restrict__ w_out, float* __restrict__ wf_out)
{
  __shared__ unsigned Hlds[4096];    // H bf16: [kg(4)][256 j][4 u32] = 16 KB
  __shared__ unsigned W1lds[1024];   // W1 bf16: [64 o][16 u32] = 4 KB
  __shared__ float    sA0[32];
  int blk = blockIdx.x, tid = threadIdx.x;
  int lane = tid&63;
  int wid = __builtin_amdgcn_readfirstlane(tid>>6);

  if(blk < 8192){
    // ------------- edge MLP for (which, i), j-chunk jc of 256 -------------
    int which = blk>>12;
    int rem = blk&4095;
    int i = rem>>2, jc = rem&3;
    const float* W0 = which? fW0:kW0; const float* b0 = which? fb0:kb0;
    const float* W1 = which? fW1:kW1; const float* b1 = which? fb1:kb1;
    const float* W2 = which? fW2:kW2; const float* b2 = which? fb2:kb2;
    float* outp = which? wf_out : w_out;
    // W1 -> bf16 LDS (row-major [o][c])
    {
      const float* src = W1 + tid*8;
      uint4 p;
      p.x=cvt2bf(src[0],src[1]); p.y=cvt2bf(src[2],src[3]);
      p.z=cvt2bf(src[4],src[5]); p.w=cvt2bf(src[6],src[7]);
      *(uint4*)&W1lds[tid*4] = p;
    }
    // a0[c] = W0[c][0]*xi + W0[c][1]*yi + b0[c]
    if(tid<32){
      int c = tid;
      float xi = -1.f + DXC*(float)(i>>5), yi = -1.f + DXC*(float)(i&31);
      sA0[c] = W0[c*4+0]*xi + W0[c*4+1]*yi + b0[c];
    }
    __syncthreads();
    // H build: one j per thread
    {
      int jloc = tid;
      int j = jc*256 + jloc;
      float xj = -1.f + DXC*(float)(j>>5), yj = -1.f + DXC*(float)(j&31);
      const float4* a04 = (const float4*)sA0;
      #pragma unroll
      for(int kg=0;kg<4;kg++){
        float h[8];
        #pragma unroll
        for(int c4=0;c4<2;c4++){
          float4 a = a04[kg*2+c4];
          int cb = (kg*8+c4*4);
          float p0 = a.x + W0[(cb+0)*4+2]*xj + W0[(cb+0)*4+3]*yj;
          float p1 = a.y + W0[(cb+1)*4+2]*xj + W0[(cb+1)*4+3]*yj;
          float p2 = a.z + W0[(cb+2)*4+2]*xj + W0[(cb+2)*4+3]*yj;
          float p3 = a.w + W0[(cb+3)*4+2]*xj + W0[(cb+3)*4+3]*yj;
          h[c4*4+0]=fmaxf(p0,SLOPEC*p0); h[c4*4+1]=fmaxf(p1,SLOPEC*p1);
          h[c4*4+2]=fmaxf(p2,SLOPEC*p2); h[c4*4+3]=fmaxf(p3,SLOPEC*p3);
        }
        uint4 hp;
        hp.x=cvt2bf(h[0],h[1]); hp.y=cvt2bf(h[2],h[3]);
        hp.z=cvt2bf(h[4],h[5]); hp.w=cvt2bf(h[6],h[7]);
        *(uint4*)&Hlds[(kg*256+jloc)*4] = hp;
      }
    }
    // per-lane o metadata: o = ot*16 + grp*4 + r
    int grp = lane>>4;
    float b1v[16], w2v[16];
    #pragma unroll
    for(int ot=0;ot<4;ot++){
      #pragma unroll
      for(int r=0;r<4;r++){
        int o = ot*16 + grp*4 + r;
        b1v[ot*4+r] = b1[o];
        w2v[ot*4+r] = W2[o];
      }
    }
    float b2s = b2[0];
    __syncthreads();
    // A-frags: lane holds W1[ot*16+(lane&15)][grp*8 .. +7]
    bf16x8 afr[4];
    #pragma unroll
    for(int ot=0;ot<4;ot++)
      afr[ot] = *(const bf16x8*)&W1lds[(ot*16 + (lane&15))*16 + grp*4];
    int jbase = wid*64;
    f32x4 zz = {0.f,0.f,0.f,0.f};
    #pragma unroll
    for(int jt=0;jt<4;jt++){
      int j0 = jbase + jt*16;
      bf16x8 bfr = *(const bf16x8*)&Hlds[(grp*256 + j0 + (lane&15))*4];
      f32x4 d0 = __builtin_amdgcn_mfma_f32_16x16x32_bf16(afr[0], bfr, zz, 0,0,0);
      f32x4 d1 = __builtin_amdgcn_mfma_f32_16x16x32_bf16(afr[1], bfr, zz, 0,0,0);
      f32x4 d2 = __builtin_amdgcn_mfma_f32_16x16x32_bf16(afr[2], bfr, zz, 0,0,0);
      f32x4 d3 = __builtin_amdgcn_mfma_f32_16x16x32_bf16(afr[3], bfr, zz, 0,0,0);
      float part = 0.f;
      #pragma unroll
      for(int r=0;r<4;r++){
        float s0 = d0[r]+b1v[r];    part = fmaf(w2v[r],    fmaxf(s0,SLOPEC*s0), part);
        float s1 = d1[r]+b1v[4+r];  part = fmaf(w2v[4+r],  fmaxf(s1,SLOPEC*s1), part);
        float s2 = d2[r]+b1v[8+r];  part = fmaf(w2v[8+r],  fmaxf(s2,SLOPEC*s2), part);
        float s3 = d3[r]+b1v[12+r]; part = fmaf(w2v[12+r], fmaxf(s3,SLOPEC*s3), part);
      }
      part += __shfl_xor(part, 16);
      part += __shfl_xor(part, 32);
      if(lane<16) outp[i*1024 + jc*256 + j0 + lane] = part + b2s;
    }
  } else if(blk < 8320){
    // ---------------- LN0 partial sums (128 blocks) ----------------
    int bb = blk-8192;
    int b = bb>>4, seg = bb&15;
    const float4* x4 = (const float4*)(xy + (size_t)b*131072 + seg*8192);
    float s=0.f, ss=0.f;
    #pragma unroll
    for(int k2=0;k2<8;k2++){
      float4 v = x4[tid + k2*256];
      s  += v.x+v.y+v.z+v.w;
      ss += v.x*v.x+v.y*v.y+v.z*v.z+v.w*v.w;
    }
    s = wsum64(s); ss = wsum64(ss);
    float* red = (float*)Hlds;
    if(lane==0){ red[wid]=s; red[4+wid]=ss; }
    __syncthreads();
    if(tid==0){
      ws[OFF_LNP + (b*16+seg)*2  ] = red[0]+red[1]+red[2]+red[3];
      ws[OFF_LNP + (b*16+seg)*2+1] = red[4]+red[5]+red[6]+red[7];
    }
  } else {
    // ---------------- prep M,u,v,c (4 blocks) ----------------
    int j = blk-8320;
    float mac[16], uac[16];
    #pragma unroll
    for(int r=0;r<16;r++){ mac[r]=0.f; uac[r]=0.f; }
    float vac=0.f, cac=0.f;
    for(int hk=0;hk<256;hk++){
      const float* wqrow = Wq + ((size_t)j*256+hk)*64;
      const float* wkrow = Wk + ((size_t)j*256+hk)*64;
      float wkl = wkrow[lane];
      float bkk = bk[j*256+hk], bqk = bq[j*256+hk];
      #pragma unroll
      for(int r=0;r<16;r++){ float wq=wqrow[wid*16+r]; mac[r]+=wq*wkl; uac[r]+=wq*bkk; }
      vac += bqk*wkl; cac += bqk*bkk;
    }
    #pragma unroll
    for(int r=0;r<16;r++) ws[OFF_M + j*4096+(wid*16+r)*64+lane] = mac[r]*SCALE;
    if(lane==0){
      #pragma unroll
      for(int r=0;r<16;r++) ws[OFF_U + j*64+wid*16+r] = uac[r]*SCALE;
    }
    if(wid==0) ws[OFF_V + j*64+lane] = vac*SCALE;
    if(tid==0) ws[OFF_C + j] = cac*SCALE;
  }
}

// ---------------- Gram of 64x64 LDS tiles ----------------
__device__ __forceinline__ void gram_tile(const float* sA, const float* sB,
    int wid, int lane, float* __restrict__ gp, float* __restrict__ gsp)
{
  float acc[16];
  #pragma unroll
  for(int q=0;q<16;q++) acc[q]=0.f;
  float gsa=0.f;
  for(int m=0;m<64;m++){
    const float4* cp = (const float4*)(sA + m*64 + wid*16);
    float bml = sB[m*64+lane];
    float4 a0=cp[0],a1=cp[1],a2=cp[2],a3=cp[3];
    acc[0]+=a0.x*bml; acc[1]+=a0.y*bml; acc[2]+=a0.z*bml; acc[3]+=a0.w*bml;
    acc[4]+=a1.x*bml; acc[5]+=a1.y*bml; acc[6]+=a1.z*bml; acc[7]+=a1.w*bml;
    acc[8]+=a2.x*bml; acc[9]+=a2.y*bml; acc[10]+=a2.z*bml; acc[11]+=a2.w*bml;
    acc[12]+=a3.x*bml; acc[13]+=a3.y*bml; acc[14]+=a3.z*bml; acc[15]+=a3.w*bml;
    gsa += bml;
  }
  #pragma unroll
  for(int q=0;q<16;q++) gp[(wid*16+q)*64+lane]=acc[q];
  if(wid==0) gsp[lane]=gsa;
}

// ---------------- T build from LDS Gram ----------------
__device__ __forceinline__ void build_T(const float* __restrict__ sG,
    const float* __restrict__ Mj, const float* __restrict__ uj,
    const float* __restrict__ vj, float cj, float gsl,
    int wid, int lane, float* __restrict__ sT, float* __restrict__ stv)
{
  float gv[64];
  #pragma unroll
  for(int c=0;c<64;c++) gv[c]=sG[c*64+lane];
  float tacc = cj*gsl;
  #pragma unroll
  for(int c=0;c<64;c++) tacc += vj[c]*gv[c];
  #pragma unroll
  for(int r=0;r<16;r++){
    const float* mrow = Mj + (wid*16+r)*64;       // wave-uniform -> s_load
    float acc = uj[wid*16+r]*gsl;
    #pragma unroll
    for(int c=0;c<64;c++) acc += mrow[c]*gv[c];
    sT[(wid*16+r)*64+lane]=acc;
  }
  if(wid==0) stv[lane]=tacc;
}

// ---------------- LN0 apply + Gram ----------------
__global__ __launch_bounds__(256) void k_ln0ag(const float* __restrict__ xy,
    const float* __restrict__ g, const float* __restrict__ bb,
    const float* __restrict__ lnp,
    float* __restrict__ Vin, float* __restrict__ Gpart, float* __restrict__ gspart)
{
  __shared__ float sV[4096];
  int b = blockIdx.x>>5, ch = blockIdx.x&31;     // grid 256
  int tid = threadIdx.x, lane = tid&63;
  int wid = __builtin_amdgcn_readfirstlane(tid>>6);
  float s=0.f, ss=0.f;
  #pragma unroll
  for(int k2=0;k2<16;k2++){ s += lnp[(b*16+k2)*2]; ss += lnp[(b*16+k2)*2+1]; }
  float mean = s*(1.0f/131072.0f);
  float var  = ss*(1.0f/131072.0f) - mean*mean;
  float inv  = 1.0f/sqrtf(var+EPSC);
  const float4* x4 = (const float4*)(xy + ((size_t)b*2048 + ch*64)*64);
  const float4* g4 = (const float4*)(g  + (size_t)ch*4096);
  const float4* b4 = (const float4*)(bb + (size_t)ch*4096);
  float4* vo4 = (float4*)(Vin + ((size_t)b*2048 + ch*64)*64);
  float4* sv4 = (float4*)sV;
  for(int e=tid;e<1024;e+=256){
    float4 xv=x4[e], gv=g4[e], bv=b4[e];
    float4 r;
    r.x=(xv.x-mean)*inv*gv.x+bv.x;
    r.y=(xv.y-mean)*inv*gv.y+bv.y;
    r.z=(xv.z-mean)*inv*gv.z+bv.z;
    r.w=(xv.w-mean)*inv*gv.w+bv.w;
    vo4[e]=r; sv4[e]=r;
  }
  __syncthreads();
  gram_tile(sV, sV, wid, lane, Gpart+((size_t)(b*32+ch))*4096, gspart+(b*32+ch)*64);
}

// ---------------- layer: redundant G-reduce + T + mid + rowLN + residual + gram ----
__global__ __launch_bounds__(256) void k_layer(
    float* __restrict__ Vin, const float* __restrict__ xy,
    const float* __restrict__ Gsrc, const float* __restrict__ gssrc,
    float* __restrict__ Gdst, float* __restrict__ gsdst,
    const float* __restrict__ Mg, const float* __restrict__ ug,
    const float* __restrict__ vg, const float* __restrict__ cg,
    const float* __restrict__ lng, const float* __restrict__ lnb,
    int j, int cross)
{
  __shared__ float sV[4096];
  __shared__ float sT[4096];
  __shared__ float sG[4096];
  __shared__ float stv[64];
  int blk = blockIdx.x, tid = threadIdx.x;       // grid 256
  int lane = tid&63;
  int wid = __builtin_amdgcn_readfirstlane(tid>>6);
  int b = blk>>5, ch = blk&31;
  float* vbase = Vin + ((size_t)b*2048 + ch*64)*64;
  {
    const float4* vb4=(const float4*)vbase;
    float4* sv4=(float4*)sV;
    #pragma unroll
    for(int e=0;e<4;e++) sv4[tid+e*256]=vb4[tid+e*256];
  }
  {
    float4 a0={0,0,0,0},a1={0,0,0,0},a2={0,0,0,0},a3={0,0,0,0};
    const float4* gp4 = (const float4*)(Gsrc + (size_t)b*32*4096) + tid*4;
    for(int c=0;c<32;c++){
      const float4* p = gp4 + c*1024;
      float4 v0=p[0],v1=p[1],v2=p[2],v3=p[3];
      a0.x+=v0.x;a0.y+=v0.y;a0.z+=v0.z;a0.w+=v0.w;
      a1.x+=v1.x;a1.y+=v1.y;a1.z+=v1.z;a1.w+=v1.w;
      a2.x+=v2.x;a2.y+=v2.y;a2.z+=v2.z;a2.w+=v2.w;
      a3.x+=v3.x;a3.y+=v3.y;a3.z+=v3.z;a3.w+=v3.w;
    }
    float4* sg4=(float4*)sG + tid*4;
    sg4[0]=a0; sg4[1]=a1; sg4[2]=a2; sg4[3]=a3;
  }
  float gsl=0.f;
  for(int c=0;c<32;c++) gsl += gssrc[(b*32+c)*64+lane];
  __syncthreads();
  build_T(sG, Mg+j*4096, ug+j*64, vg+j*64, cg[j], gsl, wid, lane, sT, stv);
  __syncthreads();
  float Tcol[64];
  #pragma unroll
  for(int c=0;c<64;c++) Tcol[c]=sT[c*64+lane];
  float tvl=stv[lane];
  float gl=lng[j*64+lane], bl=lnb[j*64+lane];
  for(int rr=0;rr<16;rr++){
    int r=wid*16+rr;
    const float4* rp=(const float4*)(sV + r*64);
    float vold = sV[r*64+lane];
    float m=tvl;
    #pragma unroll
    for(int c4=0;c4<16;c4++){
      float4 vv=rp[c4];
      m += vv.x*Tcol[c4*4]+vv.y*Tcol[c4*4+1]+vv.z*Tcol[c4*4+2]+vv.w*Tcol[c4*4+3];
    }
    m*=DXDY;
    float mean=wsum64(m)*(1.f/64.f);
    float d=m-mean;
    float var=wsum64(d*d)*(1.f/64.f);
    float y=d*(1.f/sqrtf(var+EPSC))*gl+bl+vold;
    vbase[r*64+lane]=y;
    sV[r*64+lane]=y;
  }
  __syncthreads();
  if(!cross){
    gram_tile(sV, sV, wid, lane, Gdst+((size_t)(b*32+ch))*4096, gsdst+(b*32+ch)*64);
  } else if(ch<16){
    const float4* x4=(const float4*)(xy + ((size_t)b*2048+ch*64)*64);
    float4* sx4=(float4*)sG;
    #pragma unroll
    for(int e=0;e<4;e++) sx4[tid+e*256]=x4[tid+e*256];
    __syncthreads();
    gram_tile(sV, sG, wid, lane, Gdst+((size_t)(b*16+ch))*4096, gsdst+(b*16+ch)*64);
  }
}

// ---------------- P = weight^T@Vu + weightf^T@Vf (K-split 2) + colsums -------------
__global__ __launch_bounds__(256) void k_pw(const float* __restrict__ weight,
                                            const float* __restrict__ weightf,
                                            const float* __restrict__ Vin,
                                            float* __restrict__ Pg,
                                            float* __restrict__ wspart)
{
  int bid = blockIdx.x;                           // 512 = b(8) x jjc(32) x ns(2)
  int ns = bid&1, jjc=(bid>>1)&31, b = bid>>6;
  int lane = threadIdx.x&63;
  int wid = __builtin_amdgcn_readfirstlane(threadIdx.x>>6);
  int jj0 = jjc*32 + wid*8;
  const float* Vu = Vin + (size_t)b*131072;
  const float* Vf = Vu + 65536;
  float acc[8];
  #pragma unroll
  for(int q=0;q<8;q++) acc[q]=0.f;
  if(b==0){
    float cs[8];
    #pragma unroll
    for(int q=0;q<8;q++) cs[q]=0.f;
    for(int n=ns*512;n<ns*512+512;n++){
      float vu=Vu[n*64+lane], vf=Vf[n*64+lane];
      const float* wr  = weight  + n*1024 + jj0;
      const float* wfr = weightf + n*1024 + jj0;
      #pragma unroll
      for(int q=0;q<8;q++){ float wv=wr[q], fv=wfr[q]; acc[q]+=wv*vu+fv*vf; cs[q]+=wv+fv; }
    }
    if(lane==0){
      #pragma unroll
      for(int q=0;q<8;q++) wspart[ns*1024+jj0+q]=cs[q];
    }
  } else {
    for(int n=ns*512;n<ns*512+512;n++){
      float vu=Vu[n*64+lane], vf=Vf[n*64+lane];
      const float* wr  = weight  + n*1024 + jj0;
      const float* wfr = weightf + n*1024 + jj0;
      #pragma unroll
      for(int q=0;q<8;q++){ acc[q]+=wr[q]*vu+wfr[q]*vf; }
    }
  }
  float* pp = Pg + ((size_t)(b*2+ns)*1024 + jj0)*64;
  #pragma unroll
  for(int q=0;q<8;q++) pp[q*64+lane]=acc[q];
}

// ---------------- final: redundant T3 build + out ----------------
__global__ __launch_bounds__(256) void k_final(
    const float* __restrict__ Gp2, const float* __restrict__ gsp2,
    const float* __restrict__ Mg, const float* __restrict__ ug,
    const float* __restrict__ vg, const float* __restrict__ cg,
    const float* __restrict__ Pg, const float* __restrict__ wspart,
    float* __restrict__ out)
{
  __shared__ float sG[4096];
  __shared__ float sT[4096];
  __shared__ float stv[64];
  int blk = blockIdx.x, tid = threadIdx.x;       // grid 256
  int lane = tid&63;
  int wid = __builtin_amdgcn_readfirstlane(tid>>6);
  int b = blk>>5, rg = blk&31;
  {
    float4 a0={0,0,0,0},a1={0,0,0,0},a2={0,0,0,0},a3={0,0,0,0};
    const float4* gp4 = (const float4*)(Gp2 + (size_t)b*16*4096) + tid*4;
    for(int c=0;c<16;c++){
      const float4* p = gp4 + c*1024;
      float4 v0=p[0],v1=p[1],v2=p[2],v3=p[3];
      a0.x+=v0.x;a0.y+=v0.y;a0.z+=v0.z;a0.w+=v0.w;
      a1.x+=v1.x;a1.y+=v1.y;a1.z+=v1.z;a1.w+=v1.w;
      a2.x+=v2.x;a2.y+=v2.y;a2.z+=v2.z;a2.w+=v2.w;
      a3.x+=v3.x;a3.y+=v3.y;a3.z+=v3.z;a3.w+=v3.w;
    }
    float4* sg4=(float4*)sG + tid*4;
    sg4[0]=a0; sg4[1]=a1; sg4[2]=a2; sg4[3]=a3;
  }
  float gsl=0.f;
  for(int c=0;c<16;c++) gsl += gsp2[(b*16+c)*64+tid%64];
  __syncthreads();
  build_T(sG, Mg+3*4096, ug+3*64, vg+3*64, cg[3], gsl, wid, lane, sT, stv);
  __syncthreads();
  float Tcol[64];
  #pragma unroll
  for(int c=0;c<64;c++) Tcol[c]=sT[c*64+lane];
  float t3l=stv[lane];
  for(int rw=0;rw<8;rw++){
    int jj=rg*32+wid*8+rw;
    float p = Pg[((size_t)(b*2+0)*1024+jj)*64+lane]
            + Pg[((size_t)(b*2+1)*1024+jj)*64+lane];
    float wsm = wspart[jj] + wspart[1024+jj];
    float acc=wsm*t3l;
    #pragma unroll
    for(int c=0;c<64;c++) acc += __shfl(p,c)*Tcol[c];
    out[((size_t)(b*1024)+jj)*64+lane]=acc*(DXDY*DXDY);
  }
}

extern "C" void kernel_launch(void* const* d_in, const int* in_sizes, int n_in,
                              void* d_out, int out_size, void* d_ws, size_t ws_size,
                              hipStream_t stream)
{
  (void)in_sizes; (void)n_in; (void)out_size; (void)ws_size;
  const float* xy   = (const float*)d_in[0];
  const float* kW0  = (const float*)d_in[1];
  const float* kb0  = (const float*)d_in[2];
  const float* kW1  = (const float*)d_in[3];
  const float* kb1  = (const float*)d_in[4];
  const float* kW2  = (const float*)d_in[5];
  const float* kb2  = (const float*)d_in[6];
  const float* fW0  = (const float*)d_in[7];
  const float* fb0  = (const float*)d_in[8];
  const float* fW1  = (const float*)d_in[9];
  const float* fb1  = (const float*)d_in[10];
  const float* fW2  = (const float*)d_in[11];
  const float* fb2  = (const float*)d_in[12];
  const float* Wq   = (const float*)d_in[13];
  const float* bq   = (const float*)d_in[14];
  const float* Wk   = (const float*)d_in[15];
  const float* bk   = (const float*)d_in[16];
  const float* ln0g = (const float*)d_in[17];
  const float* ln0b = (const float*)d_in[18];
  const float* lng  = (const float*)d_in[19];
  const float* lnb  = (const float*)d_in[20];
  float* out = (float*)d_out;
  float* ws  = (float*)d_ws;

  float* lnp    = ws+OFF_LNP;
  float* Mg     = ws+OFF_M;
  float* ug     = ws+OFF_U;
  float* vg     = ws+OFF_V;
  float* cg     = ws+OFF_C;
  float* wspart = ws+OFF_WSPART;
  float* Vin    = ws+OFF_VIN;
  float* weight = ws+OFF_W;
  float* weightf= ws+OFF_WF;
  float* GPA    = ws+OFF_GPA;
  float* GSA    = ws+OFF_GSA;
  float* GPB    = ws+OFF_GPB;
  float* GSB    = ws+OFF_GSB;
  float* Pg     = ws+OFF_P;

  k_mlp<<<8324, 256, 0, stream>>>(kW0,kb0,kW1,kb1,kW2,kb2,
                                  fW0,fb0,fW1,fb1,fW2,fb2,
                                  xy, Wq,bq,Wk,bk, ws, weight, weightf);
  k_ln0ag<<<256, 256, 0, stream>>>(xy, ln0g, ln0b, lnp, Vin, GPA, GSA);

  k_layer<<<256, 256, 0, stream>>>(Vin, xy, GPA, GSA, GPB, GSB,
                                   Mg, ug, vg, cg, lng, lnb, 0, 0);
  k_layer<<<256, 256, 0, stream>>>(Vin, xy, GPB, GSB, GPA, GSA,
                                   Mg, ug, vg, cg, lng, lnb, 1, 0);
  k_layer<<<256, 256, 0, stream>>>(Vin, xy, GPA, GSA, GPB, GSB,
                                   Mg, ug, vg, cg, lng, lnb, 2, 1);

  k_pw<<<512, 256, 0, stream>>>(weight, weightf, Vin, Pg, wspart);
  k_final<<<256, 256, 0, stream>>>(GPB, GSB, Mg, ug, vg, cg, Pg, wspart, out);
}

// Round 7
// 304.790 us; speedup vs baseline: 2.7708x; 1.1146x over previous
//
#include <hip/hip_runtime.h>
#include <math.h>

#define BATCH 8
constexpr float DXC   = 2.0f/31.0f;
constexpr float DXDY  = DXC*DXC;
constexpr float SCALE = 0.125f;      // 1/sqrt(64), folded into M/u/v/c
constexpr float EPSC  = 1e-5f;
constexpr float SLOPEC= 0.01f;

// ---- workspace float offsets ----
#define OFF_LNP    0u         // 256
#define OFF_M      256u       // 16384
#define OFF_U      16640u     // 256
#define OFF_V      16896u     // 256
#define OFF_C      17152u     // 16
#define OFF_WSPART 17168u     // 4096 (4 ns-partials x 1024)
#define OFF_VIN    150288u    // 1048576
#define OFF_W      1198864u   // 1048576
#define OFF_WF     2247440u   // 1048576
#define OFF_GPA    3296016u   // 1048576  (gram partials A; reused as Pg ns0/1 at the end)
#define OFF_GSA    4344592u   // 16384
#define OFF_GPB    4360976u   // 1048576  (buffer B; holds final cross-gram)
#define OFF_GSB    5409552u   // 16384
#define OFF_P      5425936u   // 1048576  (Pg ns2/3)

typedef short bf16x8 __attribute__((ext_vector_type(8)));
typedef float f32x4  __attribute__((ext_vector_type(4)));

__device__ __forceinline__ unsigned cvt2bf(float a, float b){
  unsigned r; asm("v_cvt_pk_bf16_f32 %0, %1, %2" : "=v"(r) : "v"(a), "v"(b)); return r;
}

__device__ __forceinline__ float lrelu(float x){ return fmaxf(x, SLOPEC*x); }

__device__ __forceinline__ float wsum64(float v){
  #pragma unroll
  for(int off=32; off; off>>=1) v += __shfl_xor(v, off);
  return v;
}

// ========== fused: edge MLPs (bf16 MFMA, per-i block, 4 in-block j-chunks) ==========
// Setup (W1->LDS, b1v/w2v, a0) amortized over 1024 j; launch_bounds(256,4) keeps
// the 16 MFMA + 32-reg epilogue metadata resident (round-6 VGPR=48 caused in-loop
// reload chains).
__global__ __launch_bounds__(256,4) void k_mlp(
    const float* __restrict__ kW0, const float* __restrict__ kb0,
    const float* __restrict__ kW1, const float* __restrict__ kb1,
    const float* __restrict__ kW2, const float* __restrict__ kb2,
    const float* __restrict__ fW0, const float* __restrict__ fb0,
    const float* __restrict__ fW1, const float* __restrict__ fb1,
    const float* __restrict__ fW2, const float* __restrict__ fb2,
    const float* __restrict__ xy,
    const float* __restrict__ Wq, const float* __restrict__ bq,
    const float* __restrict__ Wk, const float* __restrict__ bk,
    float* __restrict__ ws, float* __restrict__ w_out, float* __restrict__ wf_out)
{
  __shared__ unsigned Hlds[4096];    // H bf16: [kg(4)][256 j][4 u32] = 16 KB
  __shared__ unsigned W1lds[1024];   // W1 bf16: [64 o][16 u32] = 4 KB
  __shared__ float    sA0[32];
  int blk = blockIdx.x, tid = threadIdx.x;
  int lane = tid&63;
  int wid = __builtin_amdgcn_readfirstlane(tid>>6);

  if(blk < 2048){
    // ------------- edge MLP for (which, i), all 1024 j in 4 chunks -------------
    int which = blk>>10, i = blk&1023;
    const float* W0 = which? fW0:kW0; const float* b0 = which? fb0:kb0;
    const float* W1 = which? fW1:kW1; const float* b1 = which? fb1:kb1;
    const float* W2 = which? fW2:kW2; const float* b2 = which? fb2:kb2;
    float* outp = which? wf_out : w_out;
    // W1 -> bf16 LDS (row-major [o][c])
    {
      const float* src = W1 + tid*8;
      uint4 p;
      p.x=cvt2bf(src[0],src[1]); p.y=cvt2bf(src[2],src[3]);
      p.z=cvt2bf(src[4],src[5]); p.w=cvt2bf(src[6],src[7]);
      *(uint4*)&W1lds[tid*4] = p;
    }
    if(tid<32){
      int c = tid;
      float xi = -1.f + DXC*(float)(i>>5), yi = -1.f + DXC*(float)(i&31);
      sA0[c] = W0[c*4+0]*xi + W0[c*4+1]*yi + b0[c];
    }
    // per-lane o metadata: o = ot*16 + grp*4 + r   (loaded ONCE per block)
    int grp = lane>>4;
    float b1v[16], w2v[16];
    #pragma unroll
    for(int ot=0;ot<4;ot++){
      #pragma unroll
      for(int r=0;r<4;r++){
        int o = ot*16 + grp*4 + r;
        b1v[ot*4+r] = b1[o];
        w2v[ot*4+r] = W2[o];
      }
    }
    float b2s = b2[0];
    __syncthreads();
    // A-frags: lane holds W1[ot*16+(lane&15)][grp*8 .. +7]
    bf16x8 afr[4];
    #pragma unroll
    for(int ot=0;ot<4;ot++)
      afr[ot] = *(const bf16x8*)&W1lds[(ot*16 + (lane&15))*16 + grp*4];
    f32x4 zz = {0.f,0.f,0.f,0.f};

    for(int jc=0;jc<4;jc++){
      // H build: one j per thread
      {
        int j = jc*256 + tid;
        float xj = -1.f + DXC*(float)(j>>5), yj = -1.f + DXC*(float)(j&31);
        const float4* a04 = (const float4*)sA0;
        #pragma unroll
        for(int kg=0;kg<4;kg++){
          float h[8];
          #pragma unroll
          for(int c4=0;c4<2;c4++){
            float4 a = a04[kg*2+c4];
            int cb = (kg*8+c4*4);
            float p0 = a.x + W0[(cb+0)*4+2]*xj + W0[(cb+0)*4+3]*yj;
            float p1 = a.y + W0[(cb+1)*4+2]*xj + W0[(cb+1)*4+3]*yj;
            float p2 = a.z + W0[(cb+2)*4+2]*xj + W0[(cb+2)*4+3]*yj;
            float p3 = a.w + W0[(cb+3)*4+2]*xj + W0[(cb+3)*4+3]*yj;
            h[c4*4+0]=fmaxf(p0,SLOPEC*p0); h[c4*4+1]=fmaxf(p1,SLOPEC*p1);
            h[c4*4+2]=fmaxf(p2,SLOPEC*p2); h[c4*4+3]=fmaxf(p3,SLOPEC*p3);
          }
          uint4 hp;
          hp.x=cvt2bf(h[0],h[1]); hp.y=cvt2bf(h[2],h[3]);
          hp.z=cvt2bf(h[4],h[5]); hp.w=cvt2bf(h[6],h[7]);
          *(uint4*)&Hlds[(kg*256+tid)*4] = hp;
        }
      }
      __syncthreads();
      int jbase = wid*64;
      #pragma unroll
      for(int jt=0;jt<4;jt++){
        int j0 = jbase + jt*16;
        bf16x8 bfr = *(const bf16x8*)&Hlds[(grp*256 + j0 + (lane&15))*4];
        f32x4 d0 = __builtin_amdgcn_mfma_f32_16x16x32_bf16(afr[0], bfr, zz, 0,0,0);
        f32x4 d1 = __builtin_amdgcn_mfma_f32_16x16x32_bf16(afr[1], bfr, zz, 0,0,0);
        f32x4 d2 = __builtin_amdgcn_mfma_f32_16x16x32_bf16(afr[2], bfr, zz, 0,0,0);
        f32x4 d3 = __builtin_amdgcn_mfma_f32_16x16x32_bf16(afr[3], bfr, zz, 0,0,0);
        float part = 0.f;
        #pragma unroll
        for(int r=0;r<4;r++){
          float s0 = d0[r]+b1v[r];    part = fmaf(w2v[r],    fmaxf(s0,SLOPEC*s0), part);
          float s1 = d1[r]+b1v[4+r];  part = fmaf(w2v[4+r],  fmaxf(s1,SLOPEC*s1), part);
          float s2 = d2[r]+b1v[8+r];  part = fmaf(w2v[8+r],  fmaxf(s2,SLOPEC*s2), part);
          float s3 = d3[r]+b1v[12+r]; part = fmaf(w2v[12+r], fmaxf(s3,SLOPEC*s3), part);
        }
        part += __shfl_xor(part, 16);
        part += __shfl_xor(part, 32);
        if(lane<16) outp[i*1024 + jc*256 + j0 + lane] = part + b2s;
      }
      __syncthreads();
    }
  } else if(blk < 2176){
    // ---------------- LN0 partial sums (128 blocks) ----------------
    int bb = blk-2048;
    int b = bb>>4, seg = bb&15;
    const float4* x4 = (const float4*)(xy + (size_t)b*131072 + seg*8192);
    float s=0.f, ss=0.f;
    #pragma unroll
    for(int k2=0;k2<8;k2++){
      float4 v = x4[tid + k2*256];
      s  += v.x+v.y+v.z+v.w;
      ss += v.x*v.x+v.y*v.y+v.z*v.z+v.w*v.w;
    }
    s = wsum64(s); ss = wsum64(ss);
    float* red = (float*)Hlds;
    if(lane==0){ red[wid]=s; red[4+wid]=ss; }
    __syncthreads();
    if(tid==0){
      ws[OFF_LNP + (b*16+seg)*2  ] = red[0]+red[1]+red[2]+red[3];
      ws[OFF_LNP + (b*16+seg)*2+1] = red[4]+red[5]+red[6]+red[7];
    }
  } else {
    // ---------------- prep M,u,v,c (4 blocks) ----------------
    int j = blk-2176;
    float mac[16], uac[16];
    #pragma unroll
    for(int r=0;r<16;r++){ mac[r]=0.f; uac[r]=0.f; }
    float vac=0.f, cac=0.f;
    for(int hk=0;hk<256;hk++){
      const float* wqrow = Wq + ((size_t)j*256+hk)*64;
      const float* wkrow = Wk + ((size_t)j*256+hk)*64;
      float wkl = wkrow[lane];
      float bkk = bk[j*256+hk], bqk = bq[j*256+hk];
      #pragma unroll
      for(int r=0;r<16;r++){ float wq=wqrow[wid*16+r]; mac[r]+=wq*wkl; uac[r]+=wq*bkk; }
      vac += bqk*wkl; cac += bqk*bkk;
    }
    #pragma unroll
    for(int r=0;r<16;r++) ws[OFF_M + j*4096+(wid*16+r)*64+lane] = mac[r]*SCALE;
    if(lane==0){
      #pragma unroll
      for(int r=0;r<16;r++) ws[OFF_U + j*64+wid*16+r] = uac[r]*SCALE;
    }
    if(wid==0) ws[OFF_V + j*64+lane] = vac*SCALE;
    if(tid==0) ws[OFF_C + j] = cac*SCALE;
  }
}

// ---------------- Gram of 64x64 LDS tiles ----------------
__device__ __forceinline__ void gram_tile(const float* sA, const float* sB,
    int wid, int lane, float* __restrict__ gp, float* __restrict__ gsp)
{
  float acc[16];
  #pragma unroll
  for(int q=0;q<16;q++) acc[q]=0.f;
  float gsa=0.f;
  for(int m=0;m<64;m++){
    const float4* cp = (const float4*)(sA + m*64 + wid*16);
    float bml = sB[m*64+lane];
    float4 a0=cp[0],a1=cp[1],a2=cp[2],a3=cp[3];
    acc[0]+=a0.x*bml; acc[1]+=a0.y*bml; acc[2]+=a0.z*bml; acc[3]+=a0.w*bml;
    acc[4]+=a1.x*bml; acc[5]+=a1.y*bml; acc[6]+=a1.z*bml; acc[7]+=a1.w*bml;
    acc[8]+=a2.x*bml; acc[9]+=a2.y*bml; acc[10]+=a2.z*bml; acc[11]+=a2.w*bml;
    acc[12]+=a3.x*bml; acc[13]+=a3.y*bml; acc[14]+=a3.z*bml; acc[15]+=a3.w*bml;
    gsa += bml;
  }
  #pragma unroll
  for(int q=0;q<16;q++) gp[(wid*16+q)*64+lane]=acc[q];
  if(wid==0) gsp[lane]=gsa;
}

// ---------------- T build from LDS Gram ----------------
__device__ __forceinline__ void build_T(const float* __restrict__ sG,
    const float* __restrict__ Mj, const float* __restrict__ uj,
    const float* __restrict__ vj, float cj, float gsl,
    int wid, int lane, float* __restrict__ sT, float* __restrict__ stv)
{
  float gv[64];
  #pragma unroll
  for(int c=0;c<64;c++) gv[c]=sG[c*64+lane];
  float tacc = cj*gsl;
  #pragma unroll
  for(int c=0;c<64;c++) tacc += vj[c]*gv[c];
  #pragma unroll
  for(int r=0;r<16;r++){
    const float* mrow = Mj + (wid*16+r)*64;       // wave-uniform -> s_load
    float acc = uj[wid*16+r]*gsl;
    #pragma unroll
    for(int c=0;c<64;c++) acc += mrow[c]*gv[c];
    sT[(wid*16+r)*64+lane]=acc;
  }
  if(wid==0) stv[lane]=tacc;
}

// ---------------- LN0 apply + Gram ----------------
__global__ __launch_bounds__(256) void k_ln0ag(const float* __restrict__ xy,
    const float* __restrict__ g, const float* __restrict__ bb,
    const float* __restrict__ lnp,
    float* __restrict__ Vin, float* __restrict__ Gpart, float* __restrict__ gspart)
{
  __shared__ float sV[4096];
  int b = blockIdx.x>>5, ch = blockIdx.x&31;     // grid 256
  int tid = threadIdx.x, lane = tid&63;
  int wid = __builtin_amdgcn_readfirstlane(tid>>6);
  float s=0.f, ss=0.f;
  #pragma unroll
  for(int k2=0;k2<16;k2++){ s += lnp[(b*16+k2)*2]; ss += lnp[(b*16+k2)*2+1]; }
  float mean = s*(1.0f/131072.0f);
  float var  = ss*(1.0f/131072.0f) - mean*mean;
  float inv  = 1.0f/sqrtf(var+EPSC);
  const float4* x4 = (const float4*)(xy + ((size_t)b*2048 + ch*64)*64);
  const float4* g4 = (const float4*)(g  + (size_t)ch*4096);
  const float4* b4 = (const float4*)(bb + (size_t)ch*4096);
  float4* vo4 = (float4*)(Vin + ((size_t)b*2048 + ch*64)*64);
  float4* sv4 = (float4*)sV;
  for(int e=tid;e<1024;e+=256){
    float4 xv=x4[e], gv=g4[e], bv=b4[e];
    float4 r;
    r.x=(xv.x-mean)*inv*gv.x+bv.x;
    r.y=(xv.y-mean)*inv*gv.y+bv.y;
    r.z=(xv.z-mean)*inv*gv.z+bv.z;
    r.w=(xv.w-mean)*inv*gv.w+bv.w;
    vo4[e]=r; sv4[e]=r;
  }
  __syncthreads();
  gram_tile(sV, sV, wid, lane, Gpart+((size_t)(b*32+ch))*4096, gspart+(b*32+ch)*64);
}

// ---------------- layer: redundant G-reduce + T + mid + rowLN + residual + gram ----
__global__ __launch_bounds__(256) void k_layer(
    float* __restrict__ Vin, const float* __restrict__ xy,
    const float* __restrict__ Gsrc, const float* __restrict__ gssrc,
    float* __restrict__ Gdst, float* __restrict__ gsdst,
    const float* __restrict__ Mg, const float* __restrict__ ug,
    const float* __restrict__ vg, const float* __restrict__ cg,
    const float* __restrict__ lng, const float* __restrict__ lnb,
    int j, int cross)
{
  __shared__ float sV[4096];
  __shared__ float sT[4096];
  __shared__ float sG[4096];
  __shared__ float stv[64];
  int blk = blockIdx.x, tid = threadIdx.x;       // grid 256
  int lane = tid&63;
  int wid = __builtin_amdgcn_readfirstlane(tid>>6);
  int b = blk>>5, ch = blk&31;
  float* vbase = Vin + ((size_t)b*2048 + ch*64)*64;
  {
    const float4* vb4=(const float4*)vbase;
    float4* sv4=(float4*)sV;
    #pragma unroll
    for(int e=0;e<4;e++) sv4[tid+e*256]=vb4[tid+e*256];
  }
  {
    float4 a0={0,0,0,0},a1={0,0,0,0},a2={0,0,0,0},a3={0,0,0,0};
    const float4* gp4 = (const float4*)(Gsrc + (size_t)b*32*4096) + tid*4;
    for(int c=0;c<32;c++){
      const float4* p = gp4 + c*1024;
      float4 v0=p[0],v1=p[1],v2=p[2],v3=p[3];
      a0.x+=v0.x;a0.y+=v0.y;a0.z+=v0.z;a0.w+=v0.w;
      a1.x+=v1.x;a1.y+=v1.y;a1.z+=v1.z;a1.w+=v1.w;
      a2.x+=v2.x;a2.y+=v2.y;a2.z+=v2.z;a2.w+=v2.w;
      a3.x+=v3.x;a3.y+=v3.y;a3.z+=v3.z;a3.w+=v3.w;
    }
    float4* sg4=(float4*)sG + tid*4;
    sg4[0]=a0; sg4[1]=a1; sg4[2]=a2; sg4[3]=a3;
  }
  float gsl=0.f;
  for(int c=0;c<32;c++) gsl += gssrc[(b*32+c)*64+lane];
  __syncthreads();
  build_T(sG, Mg+j*4096, ug+j*64, vg+j*64, cg[j], gsl, wid, lane, sT, stv);
  __syncthreads();
  float Tcol[64];
  #pragma unroll
  for(int c=0;c<64;c++) Tcol[c]=sT[c*64+lane];
  float tvl=stv[lane];
  float gl=lng[j*64+lane], bl=lnb[j*64+lane];
  for(int rr=0;rr<16;rr++){
    int r=wid*16+rr;
    const float4* rp=(const float4*)(sV + r*64);
    float vold = sV[r*64+lane];
    float m=tvl;
    #pragma unroll
    for(int c4=0;c4<16;c4++){
      float4 vv=rp[c4];
      m += vv.x*Tcol[c4*4]+vv.y*Tcol[c4*4+1]+vv.z*Tcol[c4*4+2]+vv.w*Tcol[c4*4+3];
    }
    m*=DXDY;
    float mean=wsum64(m)*(1.f/64.f);
    float d=m-mean;
    float var=wsum64(d*d)*(1.f/64.f);
    float y=d*(1.f/sqrtf(var+EPSC))*gl+bl+vold;
    vbase[r*64+lane]=y;
    sV[r*64+lane]=y;
  }
  __syncthreads();
  if(!cross){
    gram_tile(sV, sV, wid, lane, Gdst+((size_t)(b*32+ch))*4096, gsdst+(b*32+ch)*64);
  } else if(ch<16){
    const float4* x4=(const float4*)(xy + ((size_t)b*2048+ch*64)*64);
    float4* sx4=(float4*)sG;
    #pragma unroll
    for(int e=0;e<4;e++) sx4[tid+e*256]=x4[tid+e*256];
    __syncthreads();
    gram_tile(sV, sG, wid, lane, Gdst+((size_t)(b*16+ch))*4096, gsdst+(b*16+ch)*64);
  }
}

// ---------------- P = weight^T@Vu + weightf^T@Vf (K-split 4) + colsums -------------
__global__ __launch_bounds__(256,4) void k_pw(const float* __restrict__ weight,
                                              const float* __restrict__ weightf,
                                              const float* __restrict__ Vin,
                                              float* __restrict__ PgA,
                                              float* __restrict__ PgB,
                                              float* __restrict__ wspart)
{
  int bid = blockIdx.x;                           // 1024 = b(8) x jjc(32) x ns(4)
  int ns = bid&3, jjc=(bid>>2)&31, b = bid>>7;
  int lane = threadIdx.x&63;
  int wid = __builtin_amdgcn_readfirstlane(threadIdx.x>>6);
  int jj0 = jjc*32 + wid*8;
  const float* Vu = Vin + (size_t)b*131072;
  const float* Vf = Vu + 65536;
  float acc[8];
  #pragma unroll
  for(int q=0;q<8;q++) acc[q]=0.f;
  if(b==0){
    float cs[8];
    #pragma unroll
    for(int q=0;q<8;q++) cs[q]=0.f;
    #pragma unroll 2
    for(int n=ns*256;n<ns*256+256;n++){
      float vu=Vu[n*64+lane], vf=Vf[n*64+lane];
      const float* wr  = weight  + n*1024 + jj0;
      const float* wfr = weightf + n*1024 + jj0;
      #pragma unroll
      for(int q=0;q<8;q++){ float wv=wr[q], fv=wfr[q]; acc[q]+=wv*vu+fv*vf; cs[q]+=wv+fv; }
    }
    if(lane==0){
      #pragma unroll
      for(int q=0;q<8;q++) wspart[ns*1024+jj0+q]=cs[q];
    }
  } else {
    #pragma unroll 2
    for(int n=ns*256;n<ns*256+256;n++){
      float vu=Vu[n*64+lane], vf=Vf[n*64+lane];
      const float* wr  = weight  + n*1024 + jj0;
      const float* wfr = weightf + n*1024 + jj0;
      #pragma unroll
      for(int q=0;q<8;q++){ acc[q]+=wr[q]*vu+wfr[q]*vf; }
    }
  }
  float* base = (ns<2) ? PgA : PgB;
  int nsl = ns&1;
  float* pp = base + ((size_t)(b*2+nsl)*1024 + jj0)*64;
  #pragma unroll
  for(int q=0;q<8;q++) pp[q*64+lane]=acc[q];
}

// ---------------- final: redundant T3 build + out ----------------
__global__ __launch_bounds__(256) void k_final(
    const float* __restrict__ Gp2, const float* __restrict__ gsp2,
    const float* __restrict__ Mg, const float* __restrict__ ug,
    const float* __restrict__ vg, const float* __restrict__ cg,
    const float* __restrict__ PgA, const float* __restrict__ PgB,
    const float* __restrict__ wspart,
    float* __restrict__ out)
{
  __shared__ float sG[4096];
  __shared__ float sT[4096];
  __shared__ float stv[64];
  int blk = blockIdx.x, tid = threadIdx.x;       // grid 256
  int lane = tid&63;
  int wid = __builtin_amdgcn_readfirstlane(tid>>6);
  int b = blk>>5, rg = blk&31;
  {
    float4 a0={0,0,0,0},a1={0,0,0,0},a2={0,0,0,0},a3={0,0,0,0};
    const float4* gp4 = (const float4*)(Gp2 + (size_t)b*16*4096) + tid*4;
    for(int c=0;c<16;c++){
      const float4* p = gp4 + c*1024;
      float4 v0=p[0],v1=p[1],v2=p[2],v3=p[3];
      a0.x+=v0.x;a0.y+=v0.y;a0.z+=v0.z;a0.w+=v0.w;
      a1.x+=v1.x;a1.y+=v1.y;a1.z+=v1.z;a1.w+=v1.w;
      a2.x+=v2.x;a2.y+=v2.y;a2.z+=v2.z;a2.w+=v2.w;
      a3.x+=v3.x;a3.y+=v3.y;a3.z+=v3.z;a3.w+=v3.w;
    }
    float4* sg4=(float4*)sG + tid*4;
    sg4[0]=a0; sg4[1]=a1; sg4[2]=a2; sg4[3]=a3;
  }
  float gsl=0.f;
  for(int c=0;c<16;c++) gsl += gsp2[(b*16+c)*64+lane];
  __syncthreads();
  build_T(sG, Mg+3*4096, ug+3*64, vg+3*64, cg[3], gsl, wid, lane, sT, stv);
  __syncthreads();
  float Tcol[64];
  #pragma unroll
  for(int c=0;c<64;c++) Tcol[c]=sT[c*64+lane];
  float t3l=stv[lane];
  for(int rw=0;rw<8;rw++){
    int jj=rg*32+wid*8+rw;
    float p = PgA[((size_t)(b*2+0)*1024+jj)*64+lane]
            + PgA[((size_t)(b*2+1)*1024+jj)*64+lane]
            + PgB[((size_t)(b*2+0)*1024+jj)*64+lane]
            + PgB[((size_t)(b*2+1)*1024+jj)*64+lane];
    float wsm = wspart[jj] + wspart[1024+jj] + wspart[2048+jj] + wspart[3072+jj];
    float acc=wsm*t3l;
    #pragma unroll
    for(int c=0;c<64;c++) acc += __shfl(p,c)*Tcol[c];
    out[((size_t)(b*1024)+jj)*64+lane]=acc*(DXDY*DXDY);
  }
}

extern "C" void kernel_launch(void* const* d_in, const int* in_sizes, int n_in,
                              void* d_out, int out_size, void* d_ws, size_t ws_size,
                              hipStream_t stream)
{
  (void)in_sizes; (void)n_in; (void)out_size; (void)ws_size;
  const float* xy   = (const float*)d_in[0];
  const float* kW0  = (const float*)d_in[1];
  const float* kb0  = (const float*)d_in[2];
  const float* kW1  = (const float*)d_in[3];
  const float* kb1  = (const float*)d_in[4];
  const float* kW2  = (const float*)d_in[5];
  const float* kb2  = (const float*)d_in[6];
  const float* fW0  = (const float*)d_in[7];
  const float* fb0  = (const float*)d_in[8];
  const float* fW1  = (const float*)d_in[9];
  const float* fb1  = (const float*)d_in[10];
  const float* fW2  = (const float*)d_in[11];
  const float* fb2  = (const float*)d_in[12];
  const float* Wq   = (const float*)d_in[13];
  const float* bq   = (const float*)d_in[14];
  const float* Wk   = (const float*)d_in[15];
  const float* bk   = (const float*)d_in[16];
  const float* ln0g = (const float*)d_in[17];
  const float* ln0b = (const float*)d_in[18];
  const float* lng  = (const float*)d_in[19];
  const float* lnb  = (const float*)d_in[20];
  float* out = (float*)d_out;
  float* ws  = (float*)d_ws;

  float* lnp    = ws+OFF_LNP;
  float* Mg     = ws+OFF_M;
  float* ug     = ws+OFF_U;
  float* vg     = ws+OFF_V;
  float* cg     = ws+OFF_C;
  float* wspart = ws+OFF_WSPART;
  float* Vin    = ws+OFF_VIN;
  float* weight = ws+OFF_W;
  float* weightf= ws+OFF_WF;
  float* GPA    = ws+OFF_GPA;
  float* GSA    = ws+OFF_GSA;
  float* GPB    = ws+OFF_GPB;
  float* GSB    = ws+OFF_GSB;
  float* Pg     = ws+OFF_P;

  k_mlp<<<2180, 256, 0, stream>>>(kW0,kb0,kW1,kb1,kW2,kb2,
                                  fW0,fb0,fW1,fb1,fW2,fb2,
                                  xy, Wq,bq,Wk,bk, ws, weight, weightf);
  k_ln0ag<<<256, 256, 0, stream>>>(xy, ln0g, ln0b, lnp, Vin, GPA, GSA);

  k_layer<<<256, 256, 0, stream>>>(Vin, xy, GPA, GSA, GPB, GSB,
                                   Mg, ug, vg, cg, lng, lnb, 0, 0);
  k_layer<<<256, 256, 0, stream>>>(Vin, xy, GPB, GSB, GPA, GSA,
                                   Mg, ug, vg, cg, lng, lnb, 1, 0);
  k_layer<<<256, 256, 0, stream>>>(Vin, xy, GPA, GSA, GPB, GSB,
                                   Mg, ug, vg, cg, lng, lnb, 2, 1);

  // GPA is dead after k_layer j=2 (it read GPA, wrote GPB) -> reuse for Pg ns 0/1
  k_pw<<<1024, 256, 0, stream>>>(weight, weightf, Vin, GPA, Pg, wspart);
  k_final<<<256, 256, 0, stream>>>(GPB, GSB, Mg, ug, vg, cg, GPA, Pg, wspart, out);
}

// Round 8
// 248.173 us; speedup vs baseline: 3.4030x; 1.2281x over previous
//
#include <hip/hip_runtime.h>
#include <math.h>

#define BATCH 8
constexpr float DXC   = 2.0f/31.0f;
constexpr float DXDY  = DXC*DXC;
constexpr float SCALE = 0.125f;      // 1/sqrt(64), folded into M/u/v/c
constexpr float EPSC  = 1e-5f;
constexpr float SLOPEC= 0.01f;

// ---- workspace float offsets ----
#define OFF_LNP    0u         // 256
#define OFF_M      256u       // 16384
#define OFF_U      16640u     // 256
#define OFF_V      16896u     // 256
#define OFF_C      17152u     // 16
#define OFF_WSPART 17168u     // 4096 (4 ns-partials x 1024)
#define OFF_VIN    150288u    // 1048576
#define OFF_W      1198864u   // 1048576
#define OFF_WF     2247440u   // 1048576
#define OFF_GPA    3296016u   // 1048576  (gram partials A; reused as Pg ns0/1 at the end)
#define OFF_GSA    4344592u   // 16384
#define OFF_GPB    4360976u   // 1048576  (buffer B; holds final cross-gram)
#define OFF_GSB    5409552u   // 16384
#define OFF_P      5425936u   // 1048576  (Pg ns2/3)

typedef short bf16x8 __attribute__((ext_vector_type(8)));
typedef float f32x4  __attribute__((ext_vector_type(4)));

__device__ __forceinline__ unsigned cvt2bf(float a, float b){
  unsigned r; asm("v_cvt_pk_bf16_f32 %0, %1, %2" : "=v"(r) : "v"(a), "v"(b)); return r;
}

__device__ __forceinline__ float lrelu(float x){ return fmaxf(x, SLOPEC*x); }

__device__ __forceinline__ float wsum64(float v){
  #pragma unroll
  for(int off=32; off; off>>=1) v += __shfl_xor(v, off);
  return v;
}

// ========== fused: edge MLPs (barrier-free, LDS-free, reg-resident MFMA) ==========
// B-fragment of H is computed per-lane in registers (j = lane&15, c = grp*8..+7):
// no LDS staging, no __syncthreads, waves fully independent.
__global__ __launch_bounds__(256,4) void k_mlp(
    const float* __restrict__ kW0, const float* __restrict__ kb0,
    const float* __restrict__ kW1, const float* __restrict__ kb1,
    const float* __restrict__ kW2, const float* __restrict__ kb2,
    const float* __restrict__ fW0, const float* __restrict__ fb0,
    const float* __restrict__ fW1, const float* __restrict__ fb1,
    const float* __restrict__ fW2, const float* __restrict__ fb2,
    const float* __restrict__ xy,
    const float* __restrict__ Wq, const float* __restrict__ bq,
    const float* __restrict__ Wk, const float* __restrict__ bk,
    float* __restrict__ ws, float* __restrict__ w_out, float* __restrict__ wf_out)
{
  __shared__ float red[8];
  int blk = blockIdx.x, tid = threadIdx.x;
  int lane = tid&63;
  int wid = __builtin_amdgcn_readfirstlane(tid>>6);

  if(blk < 2048){
    int which = blk>>10, i = blk&1023;
    const float* W0 = which? fW0:kW0; const float* b0 = which? fb0:kb0;
    const float* W1 = which? fW1:kW1; const float* b1 = which? fb1:kb1;
    const float* W2 = which? fW2:kW2; const float* b2 = which? fb2:kb2;
    float* outp = which? wf_out : w_out;
    int grp = lane>>4, jl = lane&15;
    float xi = -1.f + DXC*(float)(i>>5), yi = -1.f + DXC*(float)(i&31);
    // per-lane c-slice constants (c = grp*8+t)
    float a0c[8], wxc[8], wyc[8];
    #pragma unroll
    for(int t=0;t<8;t++){
      int c = grp*8+t;
      float4 w0 = *(const float4*)(W0 + c*4);
      a0c[t] = w0.x*xi + w0.y*yi + b0[c];
      wxc[t] = w0.z; wyc[t] = w0.w;
    }
    // A-frags from W1 (row o = ot*16+jl, cols grp*8..+7)
    bf16x8 afr[4];
    #pragma unroll
    for(int ot=0;ot<4;ot++){
      const float* src = W1 + (ot*16+jl)*32 + grp*8;
      uint4 p;
      p.x=cvt2bf(src[0],src[1]); p.y=cvt2bf(src[2],src[3]);
      p.z=cvt2bf(src[4],src[5]); p.w=cvt2bf(src[6],src[7]);
      afr[ot] = __builtin_bit_cast(bf16x8, p);
    }
    // epilogue metadata: lane holds D rows o = ot*16 + grp*4 + r
    float b1v[16], w2v[16];
    #pragma unroll
    for(int ot=0;ot<4;ot++){
      #pragma unroll
      for(int r=0;r<4;r++){
        int o = ot*16 + grp*4 + r;
        b1v[ot*4+r] = b1[o];
        w2v[ot*4+r] = W2[o];
      }
    }
    float b2s = b2[0];
    f32x4 zz = {0.f,0.f,0.f,0.f};
    int jbase = wid*256;
    for(int jt=0;jt<16;jt++){
      int j0 = jbase + jt*16;
      int j  = j0 + jl;
      float xj = -1.f + DXC*(float)(j>>5), yj = -1.f + DXC*(float)(j&31);
      float h[8];
      #pragma unroll
      for(int t=0;t<8;t++){
        float p = a0c[t] + wxc[t]*xj + wyc[t]*yj;
        h[t] = fmaxf(p, SLOPEC*p);
      }
      uint4 hb;
      hb.x=cvt2bf(h[0],h[1]); hb.y=cvt2bf(h[2],h[3]);
      hb.z=cvt2bf(h[4],h[5]); hb.w=cvt2bf(h[6],h[7]);
      bf16x8 bfr = __builtin_bit_cast(bf16x8, hb);
      f32x4 d0 = __builtin_amdgcn_mfma_f32_16x16x32_bf16(afr[0], bfr, zz, 0,0,0);
      f32x4 d1 = __builtin_amdgcn_mfma_f32_16x16x32_bf16(afr[1], bfr, zz, 0,0,0);
      f32x4 d2 = __builtin_amdgcn_mfma_f32_16x16x32_bf16(afr[2], bfr, zz, 0,0,0);
      f32x4 d3 = __builtin_amdgcn_mfma_f32_16x16x32_bf16(afr[3], bfr, zz, 0,0,0);
      float part = 0.f;
      #pragma unroll
      for(int r=0;r<4;r++){
        float s0 = d0[r]+b1v[r];    part = fmaf(w2v[r],    fmaxf(s0,SLOPEC*s0), part);
        float s1 = d1[r]+b1v[4+r];  part = fmaf(w2v[4+r],  fmaxf(s1,SLOPEC*s1), part);
        float s2 = d2[r]+b1v[8+r];  part = fmaf(w2v[8+r],  fmaxf(s2,SLOPEC*s2), part);
        float s3 = d3[r]+b1v[12+r]; part = fmaf(w2v[12+r], fmaxf(s3,SLOPEC*s3), part);
      }
      part += __shfl_xor(part, 16);
      part += __shfl_xor(part, 32);
      if(lane<16) outp[i*1024 + j0 + lane] = part + b2s;
    }
  } else if(blk < 2176){
    // ---------------- LN0 partial sums (128 blocks) ----------------
    int bb = blk-2048;
    int b = bb>>4, seg = bb&15;
    const float4* x4 = (const float4*)(xy + (size_t)b*131072 + seg*8192);
    float s=0.f, ss=0.f;
    #pragma unroll
    for(int k2=0;k2<8;k2++){
      float4 v = x4[tid + k2*256];
      s  += v.x+v.y+v.z+v.w;
      ss += v.x*v.x+v.y*v.y+v.z*v.z+v.w*v.w;
    }
    s = wsum64(s); ss = wsum64(ss);
    if(lane==0){ red[wid]=s; red[4+wid]=ss; }
    __syncthreads();
    if(tid==0){
      ws[OFF_LNP + (b*16+seg)*2  ] = red[0]+red[1]+red[2]+red[3];
      ws[OFF_LNP + (b*16+seg)*2+1] = red[4]+red[5]+red[6]+red[7];
    }
  } else {
    // ---------------- prep M,u,v,c (4 blocks) ----------------
    int j = blk-2176;
    float mac[16], uac[16];
    #pragma unroll
    for(int r=0;r<16;r++){ mac[r]=0.f; uac[r]=0.f; }
    float vac=0.f, cac=0.f;
    for(int hk=0;hk<256;hk++){
      const float* wqrow = Wq + ((size_t)j*256+hk)*64;
      const float* wkrow = Wk + ((size_t)j*256+hk)*64;
      float wkl = wkrow[lane];
      float bkk = bk[j*256+hk], bqk = bq[j*256+hk];
      #pragma unroll
      for(int r=0;r<16;r++){ float wq=wqrow[wid*16+r]; mac[r]+=wq*wkl; uac[r]+=wq*bkk; }
      vac += bqk*wkl; cac += bqk*bkk;
    }
    #pragma unroll
    for(int r=0;r<16;r++) ws[OFF_M + j*4096+(wid*16+r)*64+lane] = mac[r]*SCALE;
    if(lane==0){
      #pragma unroll
      for(int r=0;r<16;r++) ws[OFF_U + j*64+wid*16+r] = uac[r]*SCALE;
    }
    if(wid==0) ws[OFF_V + j*64+lane] = vac*SCALE;
    if(tid==0) ws[OFF_C + j] = cac*SCALE;
  }
}

// ---------------- Gram of 64x64 LDS tiles (8 waves: 8 cols each) ----------------
__device__ __forceinline__ void gram_tile8(const float* sA, const float* sB,
    int wid, int lane, float* __restrict__ gp, float* __restrict__ gsp)
{
  float acc[8];
  #pragma unroll
  for(int q=0;q<8;q++) acc[q]=0.f;
  float gsa=0.f;
  for(int m=0;m<64;m++){
    const float4* cp = (const float4*)(sA + m*64 + wid*8);
    float bml = sB[m*64+lane];
    float4 a0=cp[0],a1=cp[1];
    acc[0]+=a0.x*bml; acc[1]+=a0.y*bml; acc[2]+=a0.z*bml; acc[3]+=a0.w*bml;
    acc[4]+=a1.x*bml; acc[5]+=a1.y*bml; acc[6]+=a1.z*bml; acc[7]+=a1.w*bml;
    gsa += bml;
  }
  #pragma unroll
  for(int q=0;q<8;q++) gp[(wid*8+q)*64+lane]=acc[q];
  if(wid==0) gsp[lane]=gsa;
}

// ---------------- T build from LDS Gram (8 waves: 8 rows each) ----------------
__device__ __forceinline__ void build_T8(const float* __restrict__ sG,
    const float* __restrict__ Mj, const float* __restrict__ uj,
    const float* __restrict__ vj, float cj, float gsl,
    int wid, int lane, float* __restrict__ sT, float* __restrict__ stv)
{
  float gv[64];
  #pragma unroll
  for(int c=0;c<64;c++) gv[c]=sG[c*64+lane];
  float tacc = cj*gsl;
  #pragma unroll
  for(int c=0;c<64;c++) tacc += vj[c]*gv[c];
  #pragma unroll
  for(int rr=0;rr<8;rr++){
    int r = wid*8+rr;
    const float* mrow = Mj + r*64;                // wave-uniform -> s_load
    float acc = uj[r]*gsl;
    #pragma unroll
    for(int c=0;c<64;c++) acc += mrow[c]*gv[c];
    sT[r*64+lane]=acc;
  }
  if(wid==0) stv[lane]=tacc;
}

// ---------------- LN0 apply + Gram (512 threads) ----------------
__global__ __launch_bounds__(512) void k_ln0ag(const float* __restrict__ xy,
    const float* __restrict__ g, const float* __restrict__ bb,
    const float* __restrict__ lnp,
    float* __restrict__ Vin, float* __restrict__ Gpart, float* __restrict__ gspart)
{
  __shared__ float sV[4096];
  int b = blockIdx.x>>5, ch = blockIdx.x&31;     // grid 256
  int tid = threadIdx.x, lane = tid&63;
  int wid = __builtin_amdgcn_readfirstlane(tid>>6);
  float s=0.f, ss=0.f;
  #pragma unroll
  for(int k2=0;k2<16;k2++){ s += lnp[(b*16+k2)*2]; ss += lnp[(b*16+k2)*2+1]; }
  float mean = s*(1.0f/131072.0f);
  float var  = ss*(1.0f/131072.0f) - mean*mean;
  float inv  = 1.0f/sqrtf(var+EPSC);
  const float4* x4 = (const float4*)(xy + ((size_t)b*2048 + ch*64)*64);
  const float4* g4 = (const float4*)(g  + (size_t)ch*4096);
  const float4* b4 = (const float4*)(bb + (size_t)ch*4096);
  float4* vo4 = (float4*)(Vin + ((size_t)b*2048 + ch*64)*64);
  float4* sv4 = (float4*)sV;
  #pragma unroll
  for(int e=0;e<2;e++){
    int idx = tid + e*512;
    float4 xv=x4[idx], gv=g4[idx], bv=b4[idx];
    float4 r;
    r.x=(xv.x-mean)*inv*gv.x+bv.x;
    r.y=(xv.y-mean)*inv*gv.y+bv.y;
    r.z=(xv.z-mean)*inv*gv.z+bv.z;
    r.w=(xv.w-mean)*inv*gv.w+bv.w;
    vo4[idx]=r; sv4[idx]=r;
  }
  __syncthreads();
  gram_tile8(sV, sV, wid, lane, Gpart+((size_t)(b*32+ch))*4096, gspart+(b*32+ch)*64);
}

// -------- layer (512 threads): redundant G-reduce + T + mid + rowLN + res + gram ----
__global__ __launch_bounds__(512) void k_layer(
    float* __restrict__ Vin, const float* __restrict__ xy,
    const float* __restrict__ Gsrc, const float* __restrict__ gssrc,
    float* __restrict__ Gdst, float* __restrict__ gsdst,
    const float* __restrict__ Mg, const float* __restrict__ ug,
    const float* __restrict__ vg, const float* __restrict__ cg,
    const float* __restrict__ lng, const float* __restrict__ lnb,
    int j, int cross)
{
  __shared__ float sV[4096];
  __shared__ float sT[4096];
  __shared__ float sG[4096];
  __shared__ float stv[64];
  int blk = blockIdx.x, tid = threadIdx.x;       // grid 256
  int lane = tid&63;
  int wid = __builtin_amdgcn_readfirstlane(tid>>6);
  int b = blk>>5, ch = blk&31;
  float* vbase = Vin + ((size_t)b*2048 + ch*64)*64;
  {
    const float4* vb4=(const float4*)vbase;
    float4* sv4=(float4*)sV;
    #pragma unroll
    for(int e=0;e<2;e++) sv4[tid+e*512]=vb4[tid+e*512];
  }
  {
    float4 a0={0,0,0,0},a1={0,0,0,0};
    const float4* gp4 = (const float4*)(Gsrc + (size_t)b*32*4096) + tid*2;
    for(int c=0;c<32;c++){
      const float4* p = gp4 + c*1024;
      float4 v0=p[0],v1=p[1];
      a0.x+=v0.x;a0.y+=v0.y;a0.z+=v0.z;a0.w+=v0.w;
      a1.x+=v1.x;a1.y+=v1.y;a1.z+=v1.z;a1.w+=v1.w;
    }
    float4* sg4=(float4*)sG + tid*2;
    sg4[0]=a0; sg4[1]=a1;
  }
  float gsl=0.f;
  for(int c=0;c<32;c++) gsl += gssrc[(b*32+c)*64+lane];
  __syncthreads();
  build_T8(sG, Mg+j*4096, ug+j*64, vg+j*64, cg[j], gsl, wid, lane, sT, stv);
  __syncthreads();
  float Tcol[64];
  #pragma unroll
  for(int c=0;c<64;c++) Tcol[c]=sT[c*64+lane];
  float tvl=stv[lane];
  float gl=lng[j*64+lane], bl=lnb[j*64+lane];
  #pragma unroll
  for(int rr=0;rr<8;rr++){
    int r=wid*8+rr;
    const float4* rp=(const float4*)(sV + r*64);
    float vold = sV[r*64+lane];
    float m=tvl;
    #pragma unroll
    for(int c4=0;c4<16;c4++){
      float4 vv=rp[c4];
      m += vv.x*Tcol[c4*4]+vv.y*Tcol[c4*4+1]+vv.z*Tcol[c4*4+2]+vv.w*Tcol[c4*4+3];
    }
    m*=DXDY;
    float mean=wsum64(m)*(1.f/64.f);
    float d=m-mean;
    float var=wsum64(d*d)*(1.f/64.f);
    float y=d*(1.f/sqrtf(var+EPSC))*gl+bl+vold;
    vbase[r*64+lane]=y;
    sV[r*64+lane]=y;
  }
  __syncthreads();
  if(!cross){
    gram_tile8(sV, sV, wid, lane, Gdst+((size_t)(b*32+ch))*4096, gsdst+(b*32+ch)*64);
  } else if(ch<16){
    const float4* x4=(const float4*)(xy + ((size_t)b*2048+ch*64)*64);
    float4* sx4=(float4*)sG;
    #pragma unroll
    for(int e=0;e<2;e++) sx4[tid+e*512]=x4[tid+e*512];
    __syncthreads();
    gram_tile8(sV, sG, wid, lane, Gdst+((size_t)(b*16+ch))*4096, gsdst+(b*16+ch)*64);
  }
}

// ---------------- P = weight^T@Vu + weightf^T@Vf (K-split 4) + colsums -------------
__global__ __launch_bounds__(256,4) void k_pw(const float* __restrict__ weight,
                                              const float* __restrict__ weightf,
                                              const float* __restrict__ Vin,
                                              float* __restrict__ PgA,
                                              float* __restrict__ PgB,
                                              float* __restrict__ wspart)
{
  int bid = blockIdx.x;                           // 1024 = b(8) x jjc(32) x ns(4)
  int ns = bid&3, jjc=(bid>>2)&31, b = bid>>7;
  int lane = threadIdx.x&63;
  int wid = __builtin_amdgcn_readfirstlane(threadIdx.x>>6);
  int jj0 = jjc*32 + wid*8;
  const float* Vu = Vin + (size_t)b*131072;
  const float* Vf = Vu + 65536;
  float acc[8];
  #pragma unroll
  for(int q=0;q<8;q++) acc[q]=0.f;
  if(b==0){
    float cs[8];
    #pragma unroll
    for(int q=0;q<8;q++) cs[q]=0.f;
    #pragma unroll 2
    for(int n=ns*256;n<ns*256+256;n++){
      float vu=Vu[n*64+lane], vf=Vf[n*64+lane];
      const float* wr  = weight  + n*1024 + jj0;
      const float* wfr = weightf + n*1024 + jj0;
      #pragma unroll
      for(int q=0;q<8;q++){ float wv=wr[q], fv=wfr[q]; acc[q]+=wv*vu+fv*vf; cs[q]+=wv+fv; }
    }
    if(lane==0){
      #pragma unroll
      for(int q=0;q<8;q++) wspart[ns*1024+jj0+q]=cs[q];
    }
  } else {
    #pragma unroll 2
    for(int n=ns*256;n<ns*256+256;n++){
      float vu=Vu[n*64+lane], vf=Vf[n*64+lane];
      const float* wr  = weight  + n*1024 + jj0;
      const float* wfr = weightf + n*1024 + jj0;
      #pragma unroll
      for(int q=0;q<8;q++){ acc[q]+=wr[q]*vu+wfr[q]*vf; }
    }
  }
  float* base = (ns<2) ? PgA : PgB;
  int nsl = ns&1;
  float* pp = base + ((size_t)(b*2+nsl)*1024 + jj0)*64;
  #pragma unroll
  for(int q=0;q<8;q++) pp[q*64+lane]=acc[q];
}

// ---------------- final (512 threads): redundant T3 build + out ----------------
__global__ __launch_bounds__(512) void k_final(
    const float* __restrict__ Gp2, const float* __restrict__ gsp2,
    const float* __restrict__ Mg, const float* __restrict__ ug,
    const float* __restrict__ vg, const float* __restrict__ cg,
    const float* __restrict__ PgA, const float* __restrict__ PgB,
    const float* __restrict__ wspart,
    float* __restrict__ out)
{
  __shared__ float sG[4096];
  __shared__ float sT[4096];
  __shared__ float stv[64];
  int blk = blockIdx.x, tid = threadIdx.x;       // grid 256
  int lane = tid&63;
  int wid = __builtin_amdgcn_readfirstlane(tid>>6);
  int b = blk>>5, rg = blk&31;
  {
    float4 a0={0,0,0,0},a1={0,0,0,0};
    const float4* gp4 = (const float4*)(Gp2 + (size_t)b*16*4096) + tid*2;
    for(int c=0;c<16;c++){
      const float4* p = gp4 + c*1024;
      float4 v0=p[0],v1=p[1];
      a0.x+=v0.x;a0.y+=v0.y;a0.z+=v0.z;a0.w+=v0.w;
      a1.x+=v1.x;a1.y+=v1.y;a1.z+=v1.z;a1.w+=v1.w;
    }
    float4* sg4=(float4*)sG + tid*2;
    sg4[0]=a0; sg4[1]=a1;
  }
  float gsl=0.f;
  for(int c=0;c<16;c++) gsl += gsp2[(b*16+c)*64+lane];
  __syncthreads();
  build_T8(sG, Mg+3*4096, ug+3*64, vg+3*64, cg[3], gsl, wid, lane, sT, stv);
  __syncthreads();
  float Tcol[64];
  #pragma unroll
  for(int c=0;c<64;c++) Tcol[c]=sT[c*64+lane];
  float t3l=stv[lane];
  #pragma unroll
  for(int rw=0;rw<4;rw++){
    int jj=rg*32+wid*4+rw;
    float p = PgA[((size_t)(b*2+0)*1024+jj)*64+lane]
            + PgA[((size_t)(b*2+1)*1024+jj)*64+lane]
            + PgB[((size_t)(b*2+0)*1024+jj)*64+lane]
            + PgB[((size_t)(b*2+1)*1024+jj)*64+lane];
    float wsm = wspart[jj] + wspart[1024+jj] + wspart[2048+jj] + wspart[3072+jj];
    float acc=wsm*t3l;
    #pragma unroll
    for(int c=0;c<64;c++) acc += __shfl(p,c)*Tcol[c];
    out[((size_t)(b*1024)+jj)*64+lane]=acc*(DXDY*DXDY);
  }
}

extern "C" void kernel_launch(void* const* d_in, const int* in_sizes, int n_in,
                              void* d_out, int out_size, void* d_ws, size_t ws_size,
                              hipStream_t stream)
{
  (void)in_sizes; (void)n_in; (void)out_size; (void)ws_size;
  const float* xy   = (const float*)d_in[0];
  const float* kW0  = (const float*)d_in[1];
  const float* kb0  = (const float*)d_in[2];
  const float* kW1  = (const float*)d_in[3];
  const float* kb1  = (const float*)d_in[4];
  const float* kW2  = (const float*)d_in[5];
  const float* kb2  = (const float*)d_in[6];
  const float* fW0  = (const float*)d_in[7];
  const float* fb0  = (const float*)d_in[8];
  const float* fW1  = (const float*)d_in[9];
  const float* fb1  = (const float*)d_in[10];
  const float* fW2  = (const float*)d_in[11];
  const float* fb2  = (const float*)d_in[12];
  const float* Wq   = (const float*)d_in[13];
  const float* bq   = (const float*)d_in[14];
  const float* Wk   = (const float*)d_in[15];
  const float* bk   = (const float*)d_in[16];
  const float* ln0g = (const float*)d_in[17];
  const float* ln0b = (const float*)d_in[18];
  const float* lng  = (const float*)d_in[19];
  const float* lnb  = (const float*)d_in[20];
  float* out = (float*)d_out;
  float* ws  = (float*)d_ws;

  float* lnp    = ws+OFF_LNP;
  float* Mg     = ws+OFF_M;
  float* ug     = ws+OFF_U;
  float* vg     = ws+OFF_V;
  float* cg     = ws+OFF_C;
  float* wspart = ws+OFF_WSPART;
  float* Vin    = ws+OFF_VIN;
  float* weight = ws+OFF_W;
  float* weightf= ws+OFF_WF;
  float* GPA    = ws+OFF_GPA;
  float* GSA    = ws+OFF_GSA;
  float* GPB    = ws+OFF_GPB;
  float* GSB    = ws+OFF_GSB;
  float* Pg     = ws+OFF_P;

  k_mlp<<<2180, 256, 0, stream>>>(kW0,kb0,kW1,kb1,kW2,kb2,
                                  fW0,fb0,fW1,fb1,fW2,fb2,
                                  xy, Wq,bq,Wk,bk, ws, weight, weightf);
  k_ln0ag<<<256, 512, 0, stream>>>(xy, ln0g, ln0b, lnp, Vin, GPA, GSA);

  k_layer<<<256, 512, 0, stream>>>(Vin, xy, GPA, GSA, GPB, GSB,
                                   Mg, ug, vg, cg, lng, lnb, 0, 0);
  k_layer<<<256, 512, 0, stream>>>(Vin, xy, GPB, GSB, GPA, GSA,
                                   Mg, ug, vg, cg, lng, lnb, 1, 0);
  k_layer<<<256, 512, 0, stream>>>(Vin, xy, GPA, GSA, GPB, GSB,
                                   Mg, ug, vg, cg, lng, lnb, 2, 1);

  // GPA is dead after k_layer j=2 (it read GPA, wrote GPB) -> reuse for Pg ns 0/1
  k_pw<<<1024, 256, 0, stream>>>(weight, weightf, Vin, GPA, Pg, wspart);
  k_final<<<256, 512, 0, stream>>>(GPB, GSB, Mg, ug, vg, cg, GPA, Pg, wspart, out);
}